// Round 11
// baseline (6282.888 us; speedup 1.0000x reference)
//
#include <hip/hip_runtime.h>
#include <math.h>

namespace {
constexpr int N_ = 50000;
constexpr int E_ = 400000;
constexpr int F_ = 32;
constexpr int K_ = 16;
constexpr int B_ = 10;
constexpr float CUT_ = 10.0f;
constexpr float EPS_ = 1e-8f;
constexpr size_t WS_FLOATS = 108500000;
}

// Static device scratch (d_ws size unknown). ~434 MB BSS.
__device__ float g_ws[WS_FLOATS];

__constant__ float c_binom[K_] = {1.f,15.f,105.f,455.f,1365.f,3003.f,5005.f,6435.f,
                                  6435.f,5005.f,3003.f,1365.f,455.f,105.f,15.f,1.f};

__device__ __forceinline__ float sigm(float x) { return 1.f / (1.f + expf(-x)); }

// 32-float register-row load/store helpers (all indices compile-time)
__device__ __forceinline__ void ld32(const float* __restrict__ p, float* r) {
#pragma unroll
  for (int j = 0; j < 8; ++j) {
    float4 t = ((const float4*)p)[j];
    r[4*j+0]=t.x; r[4*j+1]=t.y; r[4*j+2]=t.z; r[4*j+3]=t.w;
  }
}
__device__ __forceinline__ void st32(float* __restrict__ p, const float* r) {
#pragma unroll
  for (int j = 0; j < 8; ++j)
    ((float4*)p)[j] = make_float4(r[4*j+0],r[4*j+1],r[4*j+2],r[4*j+3]);
}

// out[f] += sum_fp x[fp] * W[fp*32+f]   (W rows are wave-uniform -> scalar loads)
__device__ __forceinline__ void matvec_fwd(const float* __restrict__ W, const float* x, float* out) {
#pragma unroll
  for (int fp = 0; fp < F_; ++fp) {
    const float* row = W + fp*F_;
    float xv = x[fp];
#pragma unroll
    for (int f = 0; f < F_; ++f) out[f] = fmaf(xv, row[f], out[f]);
  }
}
// out[fp] = sum_f gvec[f] * W[fp*32+f]
__device__ __forceinline__ void matvec_T(const float* __restrict__ W, const float* gvec, float* out) {
#pragma unroll
  for (int fp = 0; fp < F_; ++fp) {
    const float* row = W + fp*F_;
    float acc = 0.f;
#pragma unroll
    for (int f = 0; f < F_; ++f) acc = fmaf(gvec[f], row[f], acc);
    out[fp] = acc;
  }
}

// ---------------- utility fills ----------------
__global__ void fill_kernel(float* __restrict__ p, size_t n, float v) {
  size_t i = (size_t)blockIdx.x * blockDim.x + threadIdx.x;
  size_t st = (size_t)gridDim.x * blockDim.x;
  for (; i < n; i += st) p[i] = v;
}

__global__ void fill_int_kernel(int* __restrict__ p, size_t n, int v) {
  size_t i = (size_t)blockIdx.x * blockDim.x + threadIdx.x;
  size_t st = (size_t)gridDim.x * blockDim.x;
  for (; i < n; i += st) p[i] = v;
}

__global__ void init_embed_kernel(float* __restrict__ s, const float* __restrict__ embed,
                                  const int* __restrict__ Z) {
  int gid = blockIdx.x * blockDim.x + threadIdx.x;
  int n = gid >> 5, f = gid & 31;
  s[gid] = embed[Z[n] * F_ + f];
}

__global__ void init_gs_kernel(float* __restrict__ Gs, const float* __restrict__ w_out) {
  int gid = blockIdx.x * blockDim.x + threadIdx.x;
  Gs[gid] = -w_out[gid & 31];
}

// ---------------- CSR build ----------------
__global__ void hist_kernel(const int* __restrict__ dst, const int* __restrict__ src,
                            int* __restrict__ cntd, int* __restrict__ cnts) {
  int e = blockIdx.x * blockDim.x + threadIdx.x;
  if (e < E_) { atomicAdd(&cntd[dst[e]], 1); atomicAdd(&cnts[src[e]], 1); }
}

__global__ __launch_bounds__(1024) void scan_kernel(
    const int* __restrict__ cntd, const int* __restrict__ cnts,
    int* __restrict__ offd, int* __restrict__ offs) {
  const int* cnt = blockIdx.x ? cnts : cntd;
  int* off = blockIdx.x ? offs : offd;
  __shared__ int part[1024];
  int tid = threadIdx.x;
  const int CH = (N_ + 1023) / 1024;  // 49
  int base = tid * CH;
  int sum = 0;
  for (int i = 0; i < CH; ++i) { int j = base + i; if (j < N_) sum += cnt[j]; }
  part[tid] = sum; __syncthreads();
  for (int d = 1; d < 1024; d <<= 1) {
    int t = (tid >= d) ? part[tid - d] : 0; __syncthreads();
    part[tid] += t; __syncthreads();
  }
  int run = (tid == 0) ? 0 : part[tid - 1];
  for (int i = 0; i < CH; ++i) {
    int j = base + i;
    if (j <= N_) { off[j] = run; if (j < N_) run += cnt[j]; }
  }
}

__global__ void cursor_init_kernel(const int* __restrict__ offd, const int* __restrict__ offs,
                                   int* __restrict__ curd, int* __restrict__ curs) {
  int i = blockIdx.x * blockDim.x + threadIdx.x;
  if (i < N_) { curd[i] = offd[i]; curs[i] = offs[i]; }
}

__global__ void scatter_kernel(const int* __restrict__ dst, const int* __restrict__ src,
                               int* __restrict__ curd, int* __restrict__ curs,
                               int* __restrict__ permd, int* __restrict__ perms) {
  int e = blockIdx.x * blockDim.x + threadIdx.x;
  if (e < E_) {
    permd[atomicAdd(&curd[dst[e]], 1)] = e;
    perms[atomicAdd(&curs[src[e]], 1)] = e;
  }
}

// ---------------- degree sort (descending), LDS-privatized ----------------
__global__ __launch_bounds__(256) void sort_hist_kernel(
    const int* __restrict__ offd, const int* __restrict__ offs, int* __restrict__ binc) {
  __shared__ int l[128];
  int tid = threadIdx.x;
  if (tid < 128) l[tid] = 0;
  __syncthreads();
  int n = blockIdx.x * 256 + tid;
  if (n < N_) {
    int bd = 63 - min(offd[n+1] - offd[n], 63);
    atomicAdd(&l[bd], 1);
    int bs = 63 - min(offs[n+1] - offs[n], 63);
    atomicAdd(&l[64 + bs], 1);
  }
  __syncthreads();
  if (tid < 128 && l[tid] > 0) atomicAdd(&binc[tid], l[tid]);
}

__global__ void sort_scan_kernel(const int* __restrict__ binc, int* __restrict__ bcur) {
  int t = threadIdx.x;  // 0: dst side, 1: src side
  if (t < 2) {
    int base = t * 64;
    int run = 0;
    for (int i = 0; i < 64; ++i) { bcur[base + i] = run; run += binc[base + i]; }
  }
}

// block-aggregated: LDS rank + one global atomic per (block,bin)
__global__ __launch_bounds__(256) void sort_scatter_kernel(
    const int* __restrict__ offd, const int* __restrict__ offs,
    int* __restrict__ bcur,
    int* __restrict__ ord_d, int* __restrict__ ord_s) {
  __shared__ int lcnt[128];
  __shared__ int lbase[128];
  int tid = threadIdx.x;
  if (tid < 128) lcnt[tid] = 0;
  __syncthreads();
  int n = blockIdx.x * 256 + tid;
  int bd = 0, bs = 0, rkd = 0, rks = 0;
  bool act = (n < N_);
  if (act) {
    bd = 63 - min(offd[n+1] - offd[n], 63);
    rkd = atomicAdd(&lcnt[bd], 1);
    bs = 64 + 63 - min(offs[n+1] - offs[n], 63);
    rks = atomicAdd(&lcnt[bs], 1);
  }
  __syncthreads();
  if (tid < 128 && lcnt[tid] > 0) lbase[tid] = atomicAdd(&bcur[tid], lcnt[tid]);
  __syncthreads();
  if (act) {
    ord_d[lbase[bd] + rkd] = n;
    ord_s[lbase[bs] + rks] = n;
  }
}

// ---------------- geometry / basis (rad + drad interleaved: rd[e][32]) ----------------
__global__ void geom_kernel(const float* __restrict__ pos, const int* __restrict__ dst,
                            const int* __restrict__ src, float* __restrict__ rd,
                            float* __restrict__ u3, float* __restrict__ rr) {
  int e = blockIdx.x * blockDim.x + threadIdx.x;
  if (e >= E_) return;
  int nd = dst[e], ns = src[e];
  float dx = pos[ns*3+0] - pos[nd*3+0];
  float dy = pos[ns*3+1] - pos[nd*3+1];
  float dz = pos[ns*3+2] - pos[nd*3+2];
  float r = sqrtf(dx*dx + dy*dy + dz*dz + EPS_);
  float t = r / (1.f + r);
  float b = 1.f - t;
  float tp[K_], bp[K_];
  tp[0] = 1.f; bp[0] = 1.f;
#pragma unroll
  for (int k = 1; k < K_; ++k) { tp[k] = tp[k-1]*t; bp[k] = bp[k-1]*b; }
  float cut = 0.f, dcut = 0.f;
  if (r < CUT_) {
    float den = (CUT_ - r) * (CUT_ + r);
    cut = expf(-r*r/den);
    dcut = cut * (-2.f*r*CUT_*CUT_/(den*den));
  }
  float inv1pr = 1.f / (1.f + r);
  float dtdr = inv1pr * inv1pr;
#pragma unroll
  for (int k = 0; k < K_; ++k) {
    float rrk = c_binom[k]*tp[k]*bp[K_-1-k];
    float d1 = (k > 0) ? k*tp[k-1]*bp[K_-1-k] : 0.f;
    float d2 = (k < K_-1) ? (K_-1-k)*tp[k]*bp[K_-2-k] : 0.f;
    float drdt = c_binom[k]*(d1 - d2);
    rd[(size_t)e*32 + k]      = rrk*cut;                     // rad_k
    rd[(size_t)e*32 + 16 + k] = drdt*dtdr*cut + rrk*dcut;    // d(rad_k)/dr
  }
  float invr = 1.f / r;
  u3[(size_t)e*3+0] = dx*invr;
  u3[(size_t)e*3+1] = dy*invr;
  u3[(size_t)e*3+2] = dz*invr;
  rr[e] = r;
}

// ---------------- forward edge pass: 32 lanes per dst node, 256-thr blocks ----------------
__global__ __launch_bounds__(256) void edge_fwd_csr(
    const int* __restrict__ ord_d,
    const int* __restrict__ dst_off, const int* __restrict__ dst_perm,
    const int* __restrict__ src,
    const float* __restrict__ rd, const float* __restrict__ u3,
    const float* __restrict__ Wb0, const float* __restrict__ Wb1, const float* __restrict__ pw,
    const float* __restrict__ s, const float* __restrict__ v,
    const float* __restrict__ ps, const float* __restrict__ pv,
    float* __restrict__ ys, float* __restrict__ yv,
    float* __restrict__ yps, float* __restrict__ ypv) {
  int gid = blockIdx.x * 256 + threadIdx.x;
  int n = ord_d[gid >> 5];
  int f = gid & 31;
  float wb0[K_], wb1[K_];
#pragma unroll
  for (int k = 0; k < K_; ++k) { wb0[k] = Wb0[k*F_+f]; wb1[k] = Wb1[k*F_+f]; }
  float pw0=pw[f],      pw1=pw[F_+f],   pw2=pw[2*F_+f], pw3=pw[3*F_+f], pw4=pw[4*F_+f];
  float pw5=pw[5*F_+f], pw6=pw[6*F_+f], pw7=pw[7*F_+f], pw8=pw[8*F_+f], pw9=pw[9*F_+f];
  float ms=0.f, mps=0.f, mv0=0.f, mv1=0.f, mv2=0.f, mpv0=0.f, mpv1=0.f, mpv2=0.f;
  int j0 = dst_off[n], j1 = dst_off[n+1];
  for (int j = j0; j < j1; ++j) {
    int e = dst_perm[j];
    int ns = src[e];
    float radl = (f < K_) ? rd[(size_t)e*32 + f] : 0.f;
    float q0 = 0.f, q1 = 0.f;
#pragma unroll
    for (int k = 0; k < K_; ++k) {
      float rk = __shfl(radl, k, 32);
      q0 += rk * wb0[k];
      q1 += rk * wb1[k];
    }
    float u0 = u3[(size_t)e*3+0], u1 = u3[(size_t)e*3+1], u2 = u3[(size_t)e*3+2];
    size_t sb = (size_t)ns*F_, vb = (size_t)ns*3*F_;
    float se = s[sb+f], pse = ps[sb+f];
    float ve0 = v[vb+f], ve1 = v[vb+F_+f], ve2 = v[vb+2*F_+f];
    float pve0 = pv[vb+f], pve1 = pv[vb+F_+f], pve2 = pv[vb+2*F_+f];
    float vu  = ve0*u0 + ve1*u1 + ve2*u2;
    float pvu = pve0*u0 + pve1*u1 + pve2*u2;
    float cpu0 = pve1*u2 - pve2*u1, cpu1 = pve2*u0 - pve0*u2, cpu2 = pve0*u1 - pve1*u0;
    float cvu0 = ve1*u2 - ve2*u1,  cvu1 = ve2*u0 - ve0*u2,  cvu2 = ve0*u1 - ve1*u0;
    ms  += pw0*se*q0  + pw1*vu*q1;
    mps += pw2*pse*q0 + pw3*pvu*q1;
    mv0 += pw4*ve0*q0 + (pw5*se*u0 + pw6*cpu0)*q1;
    mv1 += pw4*ve1*q0 + (pw5*se*u1 + pw6*cpu1)*q1;
    mv2 += pw4*ve2*q0 + (pw5*se*u2 + pw6*cpu2)*q1;
    mpv0 += pw7*pve0*q0 + (pw8*pse*u0 + pw9*cvu0)*q1;
    mpv1 += pw7*pve1*q0 + (pw8*pse*u1 + pw9*cvu1)*q1;
    mpv2 += pw7*pve2*q0 + (pw8*pse*u2 + pw9*cvu2)*q1;
  }
  size_t db = (size_t)n*F_, dvb = (size_t)n*3*F_;
  ys[db+f] = ms;
  yps[db+f] = mps;
  yv[dvb+f] = mv0;   yv[dvb+F_+f] = mv1;   yv[dvb+2*F_+f] = mv2;
  ypv[dvb+f] = mpv0; ypv[dvb+F_+f] = mpv1; ypv[dvb+2*F_+f] = mpv2;
}

// ---------------- forward node MLP: node-per-lane, scalar weights ----------------
template<bool BIAS1, bool BIAS2, bool IS_S>
__device__ __forceinline__ void fwd_channel(
    float* __restrict__ stp, const float* __restrict__ msgp, float* __restrict__ ap,
    const float* __restrict__ W1c, const float* __restrict__ W2c,
    const float* __restrict__ b1v, const float* __restrict__ b2v, float* g) {
  float y[F_];
#pragma unroll
  for (int j = 0; j < 8; ++j) {
    float4 m = ((const float4*)msgp)[j];
    float4 t = ((const float4*)stp)[j];
    y[4*j+0] = m.x + t.x; y[4*j+1] = m.y + t.y;
    y[4*j+2] = m.z + t.z; y[4*j+3] = m.w + t.w;
  }
  float acc[F_];
#pragma unroll
  for (int f = 0; f < F_; ++f) acc[f] = BIAS1 ? b1v[f] : 0.f;
  matvec_fwd(W1c, y, acc);
  st32(ap, acc);
  if (IS_S) {
#pragma unroll
    for (int f = 0; f < F_; ++f) g[f] = sigm(acc[f]);
  }
#pragma unroll
  for (int f = 0; f < F_; ++f) acc[f] *= g[f];   // h
  float o[F_];
#pragma unroll
  for (int f = 0; f < F_; ++f) o[f] = BIAS2 ? b2v[f] : 0.f;
  matvec_fwd(W2c, acc, o);
#pragma unroll
  for (int j = 0; j < 8; ++j) {
    float4 t = ((float4*)stp)[j];
    t.x += o[4*j+0]; t.y += o[4*j+1]; t.z += o[4*j+2]; t.w += o[4*j+3];
    ((float4*)stp)[j] = t;
  }
}

__global__ __launch_bounds__(64) void node_fwd_kernel(
    float* __restrict__ s, float* __restrict__ v, float* __restrict__ ps, float* __restrict__ pv,
    const float* __restrict__ ys, const float* __restrict__ yv,
    const float* __restrict__ yps, const float* __restrict__ ypv,
    const float* __restrict__ W1, const float* __restrict__ b1v,
    const float* __restrict__ W2, const float* __restrict__ b2v,
    float* __restrict__ a_s, float* __restrict__ a_v,
    float* __restrict__ a_ps, float* __restrict__ a_pv) {
  int n = blockIdx.x * 64 + threadIdx.x;
  if (n >= N_) return;
  size_t i32 = (size_t)n*F_, i96 = (size_t)n*3*F_;
  const int FF = F_*F_;
  float g[F_];
  fwd_channel<true,true,true>  (s+i32,     ys+i32,     a_s+i32,     W1,      W2,      b1v, b2v, g);
  fwd_channel<false,false,false>(v+i96,    yv+i96,     a_v+i96,     W1+FF,   W2+FF,   b1v, b2v, g);
  fwd_channel<false,false,false>(v+i96+32, yv+i96+32,  a_v+i96+32,  W1+FF,   W2+FF,   b1v, b2v, g);
  fwd_channel<false,false,false>(v+i96+64, yv+i96+64,  a_v+i96+64,  W1+FF,   W2+FF,   b1v, b2v, g);
  fwd_channel<false,false,false>(ps+i32,   yps+i32,    a_ps+i32,    W1+2*FF, W2+2*FF, b1v, b2v, g);
  fwd_channel<false,false,false>(pv+i96,   ypv+i96,    a_pv+i96,    W1+3*FF, W2+3*FF, b1v, b2v, g);
  fwd_channel<false,false,false>(pv+i96+32,ypv+i96+32, a_pv+i96+32, W1+3*FF, W2+3*FF, b1v, b2v, g);
  fwd_channel<false,false,false>(pv+i96+64,ypv+i96+64, a_pv+i96+64, W1+3*FF, W2+3*FF, b1v, b2v, g);
}

// ---------------- forward last (scalar) pass ----------------
__global__ __launch_bounds__(256) void edge_fwd_last_csr(
    const int* __restrict__ ord_d,
    const int* __restrict__ dst_off, const int* __restrict__ dst_perm,
    const int* __restrict__ src,
    const float* __restrict__ rd, const float* __restrict__ u3,
    const float* __restrict__ Wb0, const float* __restrict__ Wb1, const float* __restrict__ pwl,
    const float* __restrict__ s, const float* __restrict__ v, float* __restrict__ ys) {
  int gid = blockIdx.x * 256 + threadIdx.x;
  int n = ord_d[gid >> 5];
  int f = gid & 31;
  float wb0[K_], wb1[K_];
#pragma unroll
  for (int k = 0; k < K_; ++k) { wb0[k] = Wb0[k*F_+f]; wb1[k] = Wb1[k*F_+f]; }
  float p0 = pwl[f], p1 = pwl[F_+f];
  float m = 0.f;
  int j0 = dst_off[n], j1 = dst_off[n+1];
  for (int j = j0; j < j1; ++j) {
    int e = dst_perm[j];
    int ns = src[e];
    float radl = (f < K_) ? rd[(size_t)e*32 + f] : 0.f;
    float q0 = 0.f, q1 = 0.f;
#pragma unroll
    for (int k = 0; k < K_; ++k) {
      float rk = __shfl(radl, k, 32);
      q0 += rk * wb0[k];
      q1 += rk * wb1[k];
    }
    float u0 = u3[(size_t)e*3+0], u1 = u3[(size_t)e*3+1], u2 = u3[(size_t)e*3+2];
    float se = s[(size_t)ns*F_+f];
    size_t vb = (size_t)ns*3*F_;
    float vu = v[vb+f]*u0 + v[vb+F_+f]*u1 + v[vb+2*F_+f]*u2;
    m += p0*se*q0 + p1*vu*q1;
  }
  ys[(size_t)n*F_+f] = m;
}

__global__ __launch_bounds__(64) void node_fwd_last_kernel(
    float* __restrict__ s, const float* __restrict__ ys,
    const float* __restrict__ W1, const float* __restrict__ b1v,
    const float* __restrict__ W2, const float* __restrict__ b2v,
    float* __restrict__ a_l, const float* __restrict__ w_out,
    const float* __restrict__ ebias, const int* __restrict__ Z,
    const int* __restrict__ bseg, float* __restrict__ energy) {
  __shared__ float bins[B_];
  int tid = threadIdx.x;
  if (tid < B_) bins[tid] = 0.f;
  __syncthreads();
  int n = blockIdx.x * 64 + tid;
  if (n < N_) {
    size_t i32 = (size_t)n*F_;
    float y[F_];
#pragma unroll
    for (int j = 0; j < 8; ++j) {
      float4 m = ((const float4*)(ys+i32))[j];
      float4 t = ((const float4*)(s+i32))[j];
      y[4*j+0] = m.x + t.x; y[4*j+1] = m.y + t.y;
      y[4*j+2] = m.z + t.z; y[4*j+3] = m.w + t.w;
    }
    float a[F_];
#pragma unroll
    for (int f = 0; f < F_; ++f) a[f] = b1v[f];
    matvec_fwd(W1, y, a);
    st32(a_l+i32, a);
    float h[F_];
#pragma unroll
    for (int f = 0; f < F_; ++f) h[f] = a[f] * sigm(a[f]);
    float o[F_];
#pragma unroll
    for (int f = 0; f < F_; ++f) o[f] = b2v[f];
    matvec_fwd(W2, h, o);
    float c = 0.f;
#pragma unroll
    for (int j = 0; j < 8; ++j) {
      float4 t = ((float4*)(s+i32))[j];
      t.x += o[4*j+0]; t.y += o[4*j+1]; t.z += o[4*j+2]; t.w += o[4*j+3];
      ((float4*)(s+i32))[j] = t;
      c += t.x*w_out[4*j+0] + t.y*w_out[4*j+1] + t.z*w_out[4*j+2] + t.w*w_out[4*j+3];
    }
    c += ebias[Z[n]];
    atomicAdd(&bins[bseg[n]], c);
  }
  __syncthreads();
  if (tid < B_) atomicAdd(&energy[tid], bins[tid]);
}

// ---------------- backward last (scalar) pass ----------------
__global__ __launch_bounds__(64) void b1_last_kernel(
    float* __restrict__ s, const float* __restrict__ a_l,
    const float* __restrict__ W1, const float* __restrict__ W2, const float* __restrict__ b2v,
    float* __restrict__ Gs, float* __restrict__ ys) {
  int n = blockIdx.x * 64 + threadIdx.x;
  if (n >= N_) return;
  size_t i32 = (size_t)n*F_;
  float a[F_];
  ld32(a_l+i32, a);
  float g[F_];
#pragma unroll
  for (int f = 0; f < F_; ++f) g[f] = sigm(a[f]);
  float o[F_];
#pragma unroll
  for (int f = 0; f < F_; ++f) o[f] = b2v[f];
#pragma unroll
  for (int fp = 0; fp < F_; ++fp) {
    const float* row = W2 + fp*F_;
    float hv = a[fp]*g[fp];
#pragma unroll
    for (int f = 0; f < F_; ++f) o[f] = fmaf(hv, row[f], o[f]);
  }
#pragma unroll
  for (int j = 0; j < 8; ++j) {             // s -= o  (reconstruct s_4)
    float4 t = ((float4*)(s+i32))[j];
    t.x -= o[4*j+0]; t.y -= o[4*j+1]; t.z -= o[4*j+2]; t.w -= o[4*j+3];
    ((float4*)(s+i32))[j] = t;
  }
  float G[F_];
  ld32(Gs+i32, G);
  float gh[F_];
  matvec_T(W2, G, gh);
  float ga[F_];
#pragma unroll
  for (int f = 0; f < F_; ++f) ga[f] = gh[f] * (g[f] + a[f]*g[f]*(1.f - g[f]));
  float gy[F_];
  matvec_T(W1, ga, gy);
  st32(ys+i32, gy);
#pragma unroll
  for (int f = 0; f < F_; ++f) G[f] += gy[f];
  st32(Gs+i32, G);
}

// merged backward last edge pass: 32 lanes per SRC node
__global__ __launch_bounds__(256) void b2m_last_kernel(
    const int* __restrict__ ord_s,
    const int* __restrict__ src_off, const int* __restrict__ src_perm,
    const int* __restrict__ dst,
    const float* __restrict__ rd, const float* __restrict__ u3,
    const float* __restrict__ Wb0, const float* __restrict__ Wb1, const float* __restrict__ pwl,
    const float* __restrict__ s, const float* __restrict__ v, const float* __restrict__ ysg,
    float* __restrict__ Gs, float* __restrict__ Gv,
    float* __restrict__ grad_r, float* __restrict__ grad_u) {
  int gid = blockIdx.x * 256 + threadIdx.x;
  int n = ord_s[gid >> 5];
  int f = gid & 31;
  float wb0[K_], wb1[K_];
#pragma unroll
  for (int k = 0; k < K_; ++k) { wb0[k] = Wb0[k*F_+f]; wb1[k] = Wb1[k*F_+f]; }
  float p0 = pwl[f], p1 = pwl[F_+f];
  size_t sb = (size_t)n*F_, svb = (size_t)n*3*F_;
  float se = s[sb+f];
  float ve0 = v[svb+f], ve1 = v[svb+F_+f], ve2 = v[svb+2*F_+f];
  float ags = 0.f, agv0 = 0.f, agv1 = 0.f, agv2 = 0.f;
  int j0 = src_off[n], j1 = src_off[n+1];
  for (int j = j0; j < j1; ++j) {
    int e = src_perm[j];
    int nd = dst[e];
    float rdl = rd[(size_t)e*32 + f];   // f<16: rad_f ; f>=16: drad_{f-16}
    float q0 = 0.f, q1 = 0.f, w0 = 0.f, w1 = 0.f;
#pragma unroll
    for (int k = 0; k < K_; ++k) {
      float rk = __shfl(rdl, k, 32);
      float dk = __shfl(rdl, k + 16, 32);
      q0 += rk * wb0[k]; q1 += rk * wb1[k];
      w0 += dk * wb0[k]; w1 += dk * wb1[k];
    }
    float u0 = u3[(size_t)e*3+0], u1 = u3[(size_t)e*3+1], u2 = u3[(size_t)e*3+2];
    float gm = ysg[(size_t)nd*F_+f];
    ags += p0*q0*gm;
    float t1 = p1*q1*gm;
    agv0 += t1*u0; agv1 += t1*u1; agv2 += t1*u2;
    float vu = ve0*u0 + ve1*u1 + ve2*u2;
    float gq0 = p0*se*gm;
    float gq1 = p1*vu*gm;
    float grl = gq0*w0 + gq1*w1;
    float gu0 = t1*ve0, gu1 = t1*ve1, gu2 = t1*ve2;
#pragma unroll
    for (int off = 16; off > 0; off >>= 1) {
      grl += __shfl_xor(grl, off, 32);
      gu0 += __shfl_xor(gu0, off, 32);
      gu1 += __shfl_xor(gu1, off, 32);
      gu2 += __shfl_xor(gu2, off, 32);
    }
    if (f == 0) grad_r[e] = grl;                  // first writer of the backward chain
    if (f < 3) grad_u[(size_t)e*3+f] = (f==0 ? gu0 : (f==1 ? gu1 : gu2));
  }
  Gs[sb+f] += ags;
  Gv[svb+f] += agv0; Gv[svb+F_+f] += agv1; Gv[svb+2*F_+f] += agv2;
}

// ---------------- backward node MLP: node-per-lane, scalar weights ----------------
template<bool BIAS2, bool IS_S>
__device__ __forceinline__ void bwd_channel(
    float* __restrict__ stp, const float* __restrict__ ap,
    float* __restrict__ Gp, float* __restrict__ yp,
    const float* __restrict__ W1c, const float* __restrict__ W2c,
    const float* __restrict__ b2v, const float* g, float* dotsum) {
  float a[F_];
  ld32(ap, a);
  float o[F_];
#pragma unroll
  for (int f = 0; f < F_; ++f) o[f] = BIAS2 ? b2v[f] : 0.f;
#pragma unroll
  for (int fp = 0; fp < F_; ++fp) {          // o = W2 @ (a*g)  (fwd out recompute)
    const float* row = W2c + fp*F_;
    float hv = a[fp]*g[fp];
#pragma unroll
    for (int f = 0; f < F_; ++f) o[f] = fmaf(hv, row[f], o[f]);
  }
#pragma unroll
  for (int j = 0; j < 8; ++j) {              // state -= o (reconstruct)
    float4 t = ((float4*)stp)[j];
    t.x -= o[4*j+0]; t.y -= o[4*j+1]; t.z -= o[4*j+2]; t.w -= o[4*j+3];
    ((float4*)stp)[j] = t;
  }
  float G[F_];
  ld32(Gp, G);
  float gh[F_];
  matvec_T(W2c, G, gh);
#pragma unroll
  for (int f = 0; f < F_; ++f) dotsum[f] = fmaf(gh[f], a[f], dotsum[f]);
  float ga[F_];
  if (IS_S) {
#pragma unroll
    for (int f = 0; f < F_; ++f) ga[f] = gh[f]*g[f] + dotsum[f]*(g[f]*(1.f - g[f]));
  } else {
#pragma unroll
    for (int f = 0; f < F_; ++f) ga[f] = gh[f]*g[f];
  }
  float gy[F_];
  matvec_T(W1c, ga, gy);
  st32(yp, gy);
#pragma unroll
  for (int f = 0; f < F_; ++f) G[f] += gy[f];
  st32(Gp, G);
}

__global__ __launch_bounds__(64) void b1_kernel(
    float* __restrict__ s, float* __restrict__ v, float* __restrict__ ps, float* __restrict__ pv,
    const float* __restrict__ a_s, const float* __restrict__ a_v,
    const float* __restrict__ a_ps, const float* __restrict__ a_pv,
    const float* __restrict__ W1, const float* __restrict__ W2, const float* __restrict__ b2v,
    float* __restrict__ Gs, float* __restrict__ Gv, float* __restrict__ Gps, float* __restrict__ Gpv,
    float* __restrict__ ys, float* __restrict__ yv, float* __restrict__ yps, float* __restrict__ ypv) {
  int n = blockIdx.x * 64 + threadIdx.x;
  if (n >= N_) return;
  size_t i32 = (size_t)n*F_, i96 = (size_t)n*3*F_;
  const int FF = F_*F_;
  float g[F_];
  {
    float as0[F_];
    ld32(a_s+i32, as0);
#pragma unroll
    for (int f = 0; f < F_; ++f) g[f] = sigm(as0[f]);
  }
  float dotsum[F_];
#pragma unroll
  for (int f = 0; f < F_; ++f) dotsum[f] = 0.f;
  // non-scalar channels first (accumulate dotsum), scalar channel LAST
  bwd_channel<false,false>(v+i96,     a_v+i96,     Gv+i96,     yv+i96,     W1+FF,   W2+FF,   b2v, g, dotsum);
  bwd_channel<false,false>(v+i96+32,  a_v+i96+32,  Gv+i96+32,  yv+i96+32,  W1+FF,   W2+FF,   b2v, g, dotsum);
  bwd_channel<false,false>(v+i96+64,  a_v+i96+64,  Gv+i96+64,  yv+i96+64,  W1+FF,   W2+FF,   b2v, g, dotsum);
  bwd_channel<false,false>(ps+i32,    a_ps+i32,    Gps+i32,    yps+i32,    W1+2*FF, W2+2*FF, b2v, g, dotsum);
  bwd_channel<false,false>(pv+i96,    a_pv+i96,    Gpv+i96,    ypv+i96,    W1+3*FF, W2+3*FF, b2v, g, dotsum);
  bwd_channel<false,false>(pv+i96+32, a_pv+i96+32, Gpv+i96+32, ypv+i96+32, W1+3*FF, W2+3*FF, b2v, g, dotsum);
  bwd_channel<false,false>(pv+i96+64, a_pv+i96+64, Gpv+i96+64, ypv+i96+64, W1+3*FF, W2+3*FF, b2v, g, dotsum);
  bwd_channel<true,true>  (s+i32,     a_s+i32,     Gs+i32,     ys+i32,     W1,      W2,      b2v, g, dotsum);
}

// ---------------- merged backward edge pass: 32 lanes per SRC node ----------------
__global__ __launch_bounds__(256) void b2m_kernel(
    const int* __restrict__ ord_s,
    const int* __restrict__ src_off, const int* __restrict__ src_perm,
    const int* __restrict__ dst,
    const float* __restrict__ rd, const float* __restrict__ u3,
    const float* __restrict__ Wb0, const float* __restrict__ Wb1, const float* __restrict__ pw,
    const float* __restrict__ s, const float* __restrict__ v,
    const float* __restrict__ ps, const float* __restrict__ pv,
    const float* __restrict__ ys, const float* __restrict__ yv,
    const float* __restrict__ yps, const float* __restrict__ ypv,
    float* __restrict__ Gs, float* __restrict__ Gv, float* __restrict__ Gps, float* __restrict__ Gpv,
    float* __restrict__ grad_r, float* __restrict__ grad_u) {
  int gid = blockIdx.x * 256 + threadIdx.x;
  int n = ord_s[gid >> 5];
  int f = gid & 31;
  float wb0[K_], wb1[K_];
#pragma unroll
  for (int k = 0; k < K_; ++k) { wb0[k] = Wb0[k*F_+f]; wb1[k] = Wb1[k*F_+f]; }
  float pw0=pw[f],      pw1=pw[F_+f],   pw2=pw[2*F_+f], pw3=pw[3*F_+f], pw4=pw[4*F_+f];
  float pw5=pw[5*F_+f], pw6=pw[6*F_+f], pw7=pw[7*F_+f], pw8=pw[8*F_+f], pw9=pw[9*F_+f];
  size_t sb = (size_t)n*F_, svb = (size_t)n*3*F_;
  float se = s[sb+f], pse = ps[sb+f];
  float ve0 = v[svb+f], ve1 = v[svb+F_+f], ve2 = v[svb+2*F_+f];
  float pve0 = pv[svb+f], pve1 = pv[svb+F_+f], pve2 = pv[svb+2*F_+f];
  float ase=0.f, apse=0.f;
  float ave0=0.f, ave1=0.f, ave2=0.f, apve0=0.f, apve1=0.f, apve2=0.f;
  int j0 = src_off[n], j1 = src_off[n+1];
  for (int j = j0; j < j1; ++j) {
    int e = src_perm[j];
    int nd = dst[e];
    float rdl = rd[(size_t)e*32 + f];
    float q0 = 0.f, q1 = 0.f, w0 = 0.f, w1 = 0.f;
#pragma unroll
    for (int k = 0; k < K_; ++k) {
      float rk = __shfl(rdl, k, 32);
      float dk = __shfl(rdl, k + 16, 32);
      q0 += rk * wb0[k]; q1 += rk * wb1[k];
      w0 += dk * wb0[k]; w1 += dk * wb1[k];
    }
    float u0 = u3[(size_t)e*3+0], u1 = u3[(size_t)e*3+1], u2 = u3[(size_t)e*3+2];
    size_t db = (size_t)nd*F_, dvb = (size_t)nd*3*F_;
    float gms = ys[db+f];
    float gmv0 = yv[dvb+f], gmv1 = yv[dvb+F_+f], gmv2 = yv[dvb+2*F_+f];
    float gmps = yps[db+f];
    float gmpv0 = ypv[dvb+f], gmpv1 = ypv[dvb+F_+f], gmpv2 = ypv[dvb+2*F_+f];
    float udgmv  = u0*gmv0 + u1*gmv1 + u2*gmv2;
    float udgmpv = u0*gmpv0 + u1*gmpv1 + u2*gmpv2;
    float uxgmpv0 = u1*gmpv2 - u2*gmpv1, uxgmpv1 = u2*gmpv0 - u0*gmpv2, uxgmpv2 = u0*gmpv1 - u1*gmpv0;
    float uxgmv0  = u1*gmv2 - u2*gmv1,   uxgmv1  = u2*gmv0 - u0*gmv2,   uxgmv2  = u0*gmv1 - u1*gmv0;
    // own-state (source) grads — accumulate locally
    ase  += pw0*q0*gms  + pw5*q1*udgmv;
    apse += pw2*q0*gmps + pw8*q1*udgmpv;
    ave0 += pw1*u0*q1*gms + pw4*q0*gmv0 + pw9*q1*uxgmpv0;
    ave1 += pw1*u1*q1*gms + pw4*q0*gmv1 + pw9*q1*uxgmpv1;
    ave2 += pw1*u2*q1*gms + pw4*q0*gmv2 + pw9*q1*uxgmpv2;
    apve0 += pw3*u0*q1*gmps + pw7*q0*gmpv0 + pw6*q1*uxgmv0;
    apve1 += pw3*u1*q1*gmps + pw7*q0*gmpv1 + pw6*q1*uxgmv1;
    apve2 += pw3*u2*q1*gmps + pw7*q0*gmpv2 + pw6*q1*uxgmv2;
    // basis grads (need own state x dst grads)
    float vu  = ve0*u0 + ve1*u1 + ve2*u2;
    float pvu = pve0*u0 + pve1*u1 + pve2*u2;
    float cpu0 = pve1*u2 - pve2*u1, cpu1 = pve2*u0 - pve0*u2, cpu2 = pve0*u1 - pve1*u0;
    float cvu0 = ve1*u2 - ve2*u1,  cvu1 = ve2*u0 - ve0*u2,  cvu2 = ve0*u1 - ve1*u0;
    float gq0 = pw0*se*gms + pw2*pse*gmps
              + pw4*(ve0*gmv0 + ve1*gmv1 + ve2*gmv2)
              + pw7*(pve0*gmpv0 + pve1*gmpv1 + pve2*gmpv2);
    float gq1 = pw1*vu*gms + pw3*pvu*gmps + pw5*se*udgmv
              + pw6*(cpu0*gmv0 + cpu1*gmv1 + cpu2*gmv2)
              + pw8*pse*udgmpv
              + pw9*(cvu0*gmpv0 + cvu1*gmpv1 + cvu2*gmpv2);
    float grl = gq0*w0 + gq1*w1;   // dL/dr contribution (projected through drad)
    float gmvxpve0 = gmv1*pve2 - gmv2*pve1, gmvxpve1 = gmv2*pve0 - gmv0*pve2, gmvxpve2 = gmv0*pve1 - gmv1*pve0;
    float gmpvxve0 = gmpv1*ve2 - gmpv2*ve1, gmpvxve1 = gmpv2*ve0 - gmpv0*ve2, gmpvxve2 = gmpv0*ve1 - gmpv1*ve0;
    float gu0 = q1*(pw1*gms*ve0 + pw3*gmps*pve0 + pw5*se*gmv0 + pw6*gmvxpve0 + pw8*pse*gmpv0 + pw9*gmpvxve0);
    float gu1 = q1*(pw1*gms*ve1 + pw3*gmps*pve1 + pw5*se*gmv1 + pw6*gmvxpve1 + pw8*pse*gmpv1 + pw9*gmpvxve1);
    float gu2 = q1*(pw1*gms*ve2 + pw3*gmps*pve2 + pw5*se*gmv2 + pw6*gmvxpve2 + pw8*pse*gmpv2 + pw9*gmpvxve2);
#pragma unroll
    for (int off = 16; off > 0; off >>= 1) {
      grl += __shfl_xor(grl, off, 32);
      gu0 += __shfl_xor(gu0, off, 32);
      gu1 += __shfl_xor(gu1, off, 32);
      gu2 += __shfl_xor(gu2, off, 32);
    }
    if (f == 0) grad_r[e] += grl;
    if (f < 3) grad_u[(size_t)e*3+f] += (f==0 ? gu0 : (f==1 ? gu1 : gu2));
  }
  Gs[sb+f]  += ase;
  Gps[sb+f] += apse;
  Gv[svb+f] += ave0;  Gv[svb+F_+f] += ave1;  Gv[svb+2*F_+f] += ave2;
  Gpv[svb+f] += apve0; Gpv[svb+F_+f] += apve1; Gpv[svb+2*F_+f] += apve2;
}

// ---------------- basis backward: (grad_r, grad_u) -> forces ----------------
__global__ void basis_bwd_kernel(const int* __restrict__ dst, const int* __restrict__ src,
                                 const float* __restrict__ rr, const float* __restrict__ u3,
                                 const float* __restrict__ grad_r, const float* __restrict__ grad_u,
                                 float* __restrict__ forces) {
  int e = blockIdx.x * blockDim.x + threadIdx.x;
  if (e >= E_) return;
  float r = rr[e];
  float u0 = u3[(size_t)e*3+0], u1 = u3[(size_t)e*3+1], u2 = u3[(size_t)e*3+2];
  float gr = grad_r[e];
  float g0 = grad_u[(size_t)e*3+0], g1 = grad_u[(size_t)e*3+1], g2 = grad_u[(size_t)e*3+2];
  float gdu = g0*u0 + g1*u1 + g2*u2;
  float invr = 1.f / r;
  float gd0 = gr*u0 + (g0 - gdu*u0)*invr;
  float gd1 = gr*u1 + (g1 - gdu*u1)*invr;
  float gd2 = gr*u2 + (g2 - gdu*u2)*invr;
  int ns = src[e], nd = dst[e];
  atomicAdd(&forces[(size_t)ns*3+0], gd0);
  atomicAdd(&forces[(size_t)ns*3+1], gd1);
  atomicAdd(&forces[(size_t)ns*3+2], gd2);
  atomicAdd(&forces[(size_t)nd*3+0], -gd0);
  atomicAdd(&forces[(size_t)nd*3+1], -gd1);
  atomicAdd(&forces[(size_t)nd*3+2], -gd2);
}

// ---------------- host launcher ----------------
extern "C" void kernel_launch(void* const* d_in, const int* in_sizes, int n_in,
                              void* d_out, int out_size, void* d_ws, size_t ws_size,
                              hipStream_t stream) {
  const int*   Z     = (const int*)d_in[0];
  const float* pos   = (const float*)d_in[1];
  const int*   dst   = (const int*)d_in[2];
  const int*   src   = (const int*)d_in[3];
  const int*   bseg  = (const int*)d_in[4];
  const float* embed = (const float*)d_in[6];
  const float* Wb0   = (const float*)d_in[7];
  const float* Wb1   = (const float*)d_in[8];
  const float* pw    = (const float*)d_in[9];
  const float* Wd1   = (const float*)d_in[10];
  const float* bd1   = (const float*)d_in[11];
  const float* Wd2   = (const float*)d_in[12];
  const float* bd2   = (const float*)d_in[13];
  const float* Wb0l  = (const float*)d_in[14];
  const float* Wb1l  = (const float*)d_in[15];
  const float* pwl   = (const float*)d_in[16];
  const float* Wd1l  = (const float*)d_in[17];
  const float* bd1l  = (const float*)d_in[18];
  const float* Wd2l  = (const float*)d_in[19];
  const float* bd2l  = (const float*)d_in[20];
  const float* w_out = (const float*)d_in[21];
  const float* ebias = (const float*)d_in[22];

  float* out = (float*)d_out;
  float* energy = out;          // (B,)
  float* forces = out + B_;     // (N,3)

  float* ws = nullptr;
  (void)hipGetSymbolAddress((void**)&ws, HIP_SYMBOL(g_ws));

  const size_t NF = (size_t)N_ * F_;
  const size_t NV = (size_t)N_ * 3 * F_;
  float* rd       = ws;                       // E*32 (rad | drad)
  float* u3       = rd + (size_t)E_*32;       // E*3
  float* rr       = u3 + (size_t)E_*3;        // E
  float* s        = rr + E_;                  // N*F
  float* v        = s + NF;                   // N*3F
  float* ps       = v + NV;                   // N*F
  float* pv       = ps + NF;                  // N*3F
  float* ys       = pv + NV;                  // N*F
  float* yv       = ys + NF;                  // N*3F
  float* yps      = yv + NV;                  // N*F
  float* ypv      = yps + NF;                 // N*3F
  float* Gs       = ypv + NV;                 // N*F
  float* Gv       = Gs + NF;                  // N*3F
  float* Gps      = Gv + NV;                  // N*F
  float* Gpv      = Gps + NF;                 // N*3F
  float* grad_r   = Gpv + NV;                 // E
  float* grad_u   = grad_r + E_;              // E*3
  float* a_s      = grad_u + (size_t)E_*3;    // 4*N*F
  float* a_v      = a_s + 4*NF;               // 4*N*3F
  float* a_ps     = a_v + 4*NV;               // 4*N*F
  float* a_pv     = a_ps + 4*NF;              // 4*N*3F
  float* a_l      = a_pv + 4*NV;              // N*F
  // int region (CSR + sort)
  int* iws        = (int*)(a_l + NF);
  int* cntd       = iws;                      // N
  int* cnts       = cntd + N_;                // N
  int* dst_off    = cnts + N_;                // N+1
  int* src_off    = dst_off + (N_+1);         // N+1
  int* dst_perm   = src_off + (N_+1);         // E
  int* src_perm   = dst_perm + E_;            // E
  int* curd       = src_perm + E_;            // N
  int* curs       = curd + N_;                // N
  int* binc       = curs + N_;                // 128
  int* bcur       = binc + 128;               // 128
  int* ord_d      = bcur + 128;               // N
  int* ord_s      = ord_d + N_;               // N

  const int TB = 256;
  const int nodeBlocks = (int)(NF / TB);             // 6250 (CSR edge kernels, inits)
  const int nodeL = (N_ + 63) / 64;                  // 782 (node-per-lane MLP kernels)
  const int eThreadBlocks = (E_ + TB - 1) / TB;      // 1563
  const int nThreadBlocks = (N_ + TB - 1) / TB;      // 196

  // ---- CSR build + degree sort ----
  fill_int_kernel<<<256, TB, 0, stream>>>(cntd, (size_t)2*N_, 0);
  fill_int_kernel<<<1, 128, 0, stream>>>(binc, 128, 0);
  hist_kernel<<<eThreadBlocks, TB, 0, stream>>>(dst, src, cntd, cnts);
  scan_kernel<<<2, 1024, 0, stream>>>(cntd, cnts, dst_off, src_off);
  cursor_init_kernel<<<nThreadBlocks, TB, 0, stream>>>(dst_off, src_off, curd, curs);
  scatter_kernel<<<eThreadBlocks, TB, 0, stream>>>(dst, src, curd, curs, dst_perm, src_perm);
  sort_hist_kernel<<<nThreadBlocks, TB, 0, stream>>>(dst_off, src_off, binc);
  sort_scan_kernel<<<1, 64, 0, stream>>>(binc, bcur);
  sort_scatter_kernel<<<nThreadBlocks, TB, 0, stream>>>(dst_off, src_off, bcur, ord_d, ord_s);

  // ---- init state + geometry ----
  fill_kernel<<<2048, TB, 0, stream>>>(v, 7*NF, 0.f);  // v,ps,pv = 0
  init_embed_kernel<<<nodeBlocks, TB, 0, stream>>>(s, embed, Z);
  geom_kernel<<<eThreadBlocks, TB, 0, stream>>>(pos, dst, src, rd, u3, rr);

  // ---- 4 full equivariant passes ----
  for (int i = 0; i < 4; ++i) {
    edge_fwd_csr<<<nodeBlocks, TB, 0, stream>>>(
        ord_d, dst_off, dst_perm, src, rd, u3,
        Wb0 + (size_t)i*K_*F_, Wb1 + (size_t)i*K_*F_, pw + (size_t)i*10*F_,
        s, v, ps, pv, ys, yv, yps, ypv);
    node_fwd_kernel<<<nodeL, 64, 0, stream>>>(
        s, v, ps, pv, ys, yv, yps, ypv,
        Wd1 + (size_t)i*4*F_*F_, bd1 + (size_t)i*F_,
        Wd2 + (size_t)i*4*F_*F_, bd2 + (size_t)i*F_,
        a_s + i*NF, a_v + i*NV, a_ps + i*NF, a_pv + i*NV);
  }

  // ---- last scalar pass ----
  fill_kernel<<<592, TB, 0, stream>>>(out, (size_t)(B_ + N_*3), 0.f);
  edge_fwd_last_csr<<<nodeBlocks, TB, 0, stream>>>(
      ord_d, dst_off, dst_perm, src, rd, u3, Wb0l, Wb1l, pwl, s, v, ys);
  node_fwd_last_kernel<<<nodeL, 64, 0, stream>>>(
      s, ys, Wd1l, bd1l, Wd2l, bd2l, a_l, w_out, ebias, Z, bseg, energy);

  // ---- backward init ----
  init_gs_kernel<<<nodeBlocks, TB, 0, stream>>>(Gs, w_out);
  fill_kernel<<<2048, TB, 0, stream>>>(Gv, 7*NF, 0.f);

  // ---- last pass backward (writes grad_r/grad_u, no fill needed) ----
  b1_last_kernel<<<nodeL, 64, 0, stream>>>(s, a_l, Wd1l, Wd2l, bd2l, Gs, ys);
  b2m_last_kernel<<<nodeBlocks, TB, 0, stream>>>(
      ord_s, src_off, src_perm, dst, rd, u3, Wb0l, Wb1l, pwl, s, v, ys,
      Gs, Gv, grad_r, grad_u);

  // ---- 4 full passes backward ----
  for (int i = 3; i >= 0; --i) {
    b1_kernel<<<nodeL, 64, 0, stream>>>(
        s, v, ps, pv,
        a_s + i*NF, a_v + i*NV, a_ps + i*NF, a_pv + i*NV,
        Wd1 + (size_t)i*4*F_*F_, Wd2 + (size_t)i*4*F_*F_, bd2 + (size_t)i*F_,
        Gs, Gv, Gps, Gpv, ys, yv, yps, ypv);
    b2m_kernel<<<nodeBlocks, TB, 0, stream>>>(
        ord_s, src_off, src_perm, dst, rd, u3,
        Wb0 + (size_t)i*K_*F_, Wb1 + (size_t)i*K_*F_, pw + (size_t)i*10*F_,
        s, v, ps, pv, ys, yv, yps, ypv, Gs, Gv, Gps, Gpv, grad_r, grad_u);
  }

  // ---- basis backward -> forces ----
  basis_bwd_kernel<<<eThreadBlocks, TB, 0, stream>>>(
      dst, src, rr, u3, grad_r, grad_u, forces);
}

// Round 12
// 3154.682 us; speedup vs baseline: 1.9916x; 1.9916x over previous
//
#include <hip/hip_runtime.h>
#include <math.h>

namespace {
constexpr int N_ = 50000;
constexpr int E_ = 400000;
constexpr int F_ = 32;
constexpr int K_ = 16;
constexpr int B_ = 10;
constexpr float CUT_ = 10.0f;
constexpr float EPS_ = 1e-8f;
constexpr size_t WS_FLOATS = 108500000;
}

// Static device scratch (d_ws size unknown). ~434 MB BSS.
__device__ float g_ws[WS_FLOATS];

__constant__ float c_binom[K_] = {1.f,15.f,105.f,455.f,1365.f,3003.f,5005.f,6435.f,
                                  6435.f,5005.f,3003.f,1365.f,455.f,105.f,15.f,1.f};

__device__ __forceinline__ float sigm(float x) { return 1.f / (1.f + expf(-x)); }

// ---------------- utility fills ----------------
__global__ void fill_kernel(float* __restrict__ p, size_t n, float v) {
  size_t i = (size_t)blockIdx.x * blockDim.x + threadIdx.x;
  size_t st = (size_t)gridDim.x * blockDim.x;
  for (; i < n; i += st) p[i] = v;
}

__global__ void fill_int_kernel(int* __restrict__ p, size_t n, int v) {
  size_t i = (size_t)blockIdx.x * blockDim.x + threadIdx.x;
  size_t st = (size_t)gridDim.x * blockDim.x;
  for (; i < n; i += st) p[i] = v;
}

__global__ void init_embed_kernel(float* __restrict__ s, const float* __restrict__ embed,
                                  const int* __restrict__ Z) {
  int gid = blockIdx.x * blockDim.x + threadIdx.x;
  int n = gid >> 5, f = gid & 31;
  s[gid] = embed[Z[n] * F_ + f];
}

__global__ void init_gs_kernel(float* __restrict__ Gs, const float* __restrict__ w_out) {
  int gid = blockIdx.x * blockDim.x + threadIdx.x;
  Gs[gid] = -w_out[gid & 31];
}

// ---------------- CSR build ----------------
__global__ void hist_kernel(const int* __restrict__ dst, const int* __restrict__ src,
                            int* __restrict__ cntd, int* __restrict__ cnts) {
  int e = blockIdx.x * blockDim.x + threadIdx.x;
  if (e < E_) { atomicAdd(&cntd[dst[e]], 1); atomicAdd(&cnts[src[e]], 1); }
}

__global__ __launch_bounds__(1024) void scan_kernel(
    const int* __restrict__ cntd, const int* __restrict__ cnts,
    int* __restrict__ offd, int* __restrict__ offs) {
  const int* cnt = blockIdx.x ? cnts : cntd;
  int* off = blockIdx.x ? offs : offd;
  __shared__ int part[1024];
  int tid = threadIdx.x;
  const int CH = (N_ + 1023) / 1024;  // 49
  int base = tid * CH;
  int sum = 0;
  for (int i = 0; i < CH; ++i) { int j = base + i; if (j < N_) sum += cnt[j]; }
  part[tid] = sum; __syncthreads();
  for (int d = 1; d < 1024; d <<= 1) {
    int t = (tid >= d) ? part[tid - d] : 0; __syncthreads();
    part[tid] += t; __syncthreads();
  }
  int run = (tid == 0) ? 0 : part[tid - 1];
  for (int i = 0; i < CH; ++i) {
    int j = base + i;
    if (j <= N_) { off[j] = run; if (j < N_) run += cnt[j]; }
  }
}

__global__ void cursor_init_kernel(const int* __restrict__ offd, const int* __restrict__ offs,
                                   int* __restrict__ curd, int* __restrict__ curs) {
  int i = blockIdx.x * blockDim.x + threadIdx.x;
  if (i < N_) { curd[i] = offd[i]; curs[i] = offs[i]; }
}

__global__ void scatter_kernel(const int* __restrict__ dst, const int* __restrict__ src,
                               int* __restrict__ curd, int* __restrict__ curs,
                               int* __restrict__ permd, int* __restrict__ perms) {
  int e = blockIdx.x * blockDim.x + threadIdx.x;
  if (e < E_) {
    permd[atomicAdd(&curd[dst[e]], 1)] = e;
    perms[atomicAdd(&curs[src[e]], 1)] = e;
  }
}

// ---------------- degree sort (descending), LDS-privatized ----------------
__global__ __launch_bounds__(256) void sort_hist_kernel(
    const int* __restrict__ offd, const int* __restrict__ offs, int* __restrict__ binc) {
  __shared__ int l[128];
  int tid = threadIdx.x;
  if (tid < 128) l[tid] = 0;
  __syncthreads();
  int n = blockIdx.x * 256 + tid;
  if (n < N_) {
    int bd = 63 - min(offd[n+1] - offd[n], 63);
    atomicAdd(&l[bd], 1);
    int bs = 63 - min(offs[n+1] - offs[n], 63);
    atomicAdd(&l[64 + bs], 1);
  }
  __syncthreads();
  if (tid < 128 && l[tid] > 0) atomicAdd(&binc[tid], l[tid]);
}

__global__ void sort_scan_kernel(const int* __restrict__ binc, int* __restrict__ bcur) {
  int t = threadIdx.x;  // 0: dst side, 1: src side
  if (t < 2) {
    int base = t * 64;
    int run = 0;
    for (int i = 0; i < 64; ++i) { bcur[base + i] = run; run += binc[base + i]; }
  }
}

// block-aggregated: LDS rank + one global atomic per (block,bin)
__global__ __launch_bounds__(256) void sort_scatter_kernel(
    const int* __restrict__ offd, const int* __restrict__ offs,
    int* __restrict__ bcur,
    int* __restrict__ ord_d, int* __restrict__ ord_s) {
  __shared__ int lcnt[128];
  __shared__ int lbase[128];
  int tid = threadIdx.x;
  if (tid < 128) lcnt[tid] = 0;
  __syncthreads();
  int n = blockIdx.x * 256 + tid;
  int bd = 0, bs = 0, rkd = 0, rks = 0;
  bool act = (n < N_);
  if (act) {
    bd = 63 - min(offd[n+1] - offd[n], 63);
    rkd = atomicAdd(&lcnt[bd], 1);
    bs = 64 + 63 - min(offs[n+1] - offs[n], 63);
    rks = atomicAdd(&lcnt[bs], 1);
  }
  __syncthreads();
  if (tid < 128 && lcnt[tid] > 0) lbase[tid] = atomicAdd(&bcur[tid], lcnt[tid]);
  __syncthreads();
  if (act) {
    ord_d[lbase[bd] + rkd] = n;
    ord_s[lbase[bs] + rks] = n;
  }
}

// ---------------- geometry / basis (rad + drad interleaved: rd[e][32]) ----------------
__global__ void geom_kernel(const float* __restrict__ pos, const int* __restrict__ dst,
                            const int* __restrict__ src, float* __restrict__ rd,
                            float* __restrict__ u3, float* __restrict__ rr) {
  int e = blockIdx.x * blockDim.x + threadIdx.x;
  if (e >= E_) return;
  int nd = dst[e], ns = src[e];
  float dx = pos[ns*3+0] - pos[nd*3+0];
  float dy = pos[ns*3+1] - pos[nd*3+1];
  float dz = pos[ns*3+2] - pos[nd*3+2];
  float r = sqrtf(dx*dx + dy*dy + dz*dz + EPS_);
  float t = r / (1.f + r);
  float b = 1.f - t;
  float tp[K_], bp[K_];
  tp[0] = 1.f; bp[0] = 1.f;
#pragma unroll
  for (int k = 1; k < K_; ++k) { tp[k] = tp[k-1]*t; bp[k] = bp[k-1]*b; }
  float cut = 0.f, dcut = 0.f;
  if (r < CUT_) {
    float den = (CUT_ - r) * (CUT_ + r);
    cut = expf(-r*r/den);
    dcut = cut * (-2.f*r*CUT_*CUT_/(den*den));
  }
  float inv1pr = 1.f / (1.f + r);
  float dtdr = inv1pr * inv1pr;
#pragma unroll
  for (int k = 0; k < K_; ++k) {
    float rrk = c_binom[k]*tp[k]*bp[K_-1-k];
    float d1 = (k > 0) ? k*tp[k-1]*bp[K_-1-k] : 0.f;
    float d2 = (k < K_-1) ? (K_-1-k)*tp[k]*bp[K_-2-k] : 0.f;
    float drdt = c_binom[k]*(d1 - d2);
    rd[(size_t)e*32 + k]      = rrk*cut;                     // rad_k
    rd[(size_t)e*32 + 16 + k] = drdt*dtdr*cut + rrk*dcut;    // d(rad_k)/dr
  }
  float invr = 1.f / r;
  u3[(size_t)e*3+0] = dx*invr;
  u3[(size_t)e*3+1] = dy*invr;
  u3[(size_t)e*3+2] = dz*invr;
  rr[e] = r;
}

// ---------------- forward edge pass: 32 lanes per dst node, 256-thr blocks ----------------
__global__ __launch_bounds__(256) void edge_fwd_csr(
    const int* __restrict__ ord_d,
    const int* __restrict__ dst_off, const int* __restrict__ dst_perm,
    const int* __restrict__ src,
    const float* __restrict__ rd, const float* __restrict__ u3,
    const float* __restrict__ Wb0, const float* __restrict__ Wb1, const float* __restrict__ pw,
    const float* __restrict__ s, const float* __restrict__ v,
    const float* __restrict__ ps, const float* __restrict__ pv,
    float* __restrict__ ys, float* __restrict__ yv,
    float* __restrict__ yps, float* __restrict__ ypv) {
  int gid = blockIdx.x * 256 + threadIdx.x;
  int n = ord_d[gid >> 5];
  int f = gid & 31;
  float wb0[K_], wb1[K_];
#pragma unroll
  for (int k = 0; k < K_; ++k) { wb0[k] = Wb0[k*F_+f]; wb1[k] = Wb1[k*F_+f]; }
  float pw0=pw[f],      pw1=pw[F_+f],   pw2=pw[2*F_+f], pw3=pw[3*F_+f], pw4=pw[4*F_+f];
  float pw5=pw[5*F_+f], pw6=pw[6*F_+f], pw7=pw[7*F_+f], pw8=pw[8*F_+f], pw9=pw[9*F_+f];
  float ms=0.f, mps=0.f, mv0=0.f, mv1=0.f, mv2=0.f, mpv0=0.f, mpv1=0.f, mpv2=0.f;
  int j0 = dst_off[n], j1 = dst_off[n+1];
  for (int j = j0; j < j1; ++j) {
    int e = dst_perm[j];
    int ns = src[e];
    float radl = (f < K_) ? rd[(size_t)e*32 + f] : 0.f;
    float q0 = 0.f, q1 = 0.f;
#pragma unroll
    for (int k = 0; k < K_; ++k) {
      float rk = __shfl(radl, k, 32);
      q0 += rk * wb0[k];
      q1 += rk * wb1[k];
    }
    float u0 = u3[(size_t)e*3+0], u1 = u3[(size_t)e*3+1], u2 = u3[(size_t)e*3+2];
    size_t sb = (size_t)ns*F_, vb = (size_t)ns*3*F_;
    float se = s[sb+f], pse = ps[sb+f];
    float ve0 = v[vb+f], ve1 = v[vb+F_+f], ve2 = v[vb+2*F_+f];
    float pve0 = pv[vb+f], pve1 = pv[vb+F_+f], pve2 = pv[vb+2*F_+f];
    float vu  = ve0*u0 + ve1*u1 + ve2*u2;
    float pvu = pve0*u0 + pve1*u1 + pve2*u2;
    float cpu0 = pve1*u2 - pve2*u1, cpu1 = pve2*u0 - pve0*u2, cpu2 = pve0*u1 - pve1*u0;
    float cvu0 = ve1*u2 - ve2*u1,  cvu1 = ve2*u0 - ve0*u2,  cvu2 = ve0*u1 - ve1*u0;
    ms  += pw0*se*q0  + pw1*vu*q1;
    mps += pw2*pse*q0 + pw3*pvu*q1;
    mv0 += pw4*ve0*q0 + (pw5*se*u0 + pw6*cpu0)*q1;
    mv1 += pw4*ve1*q0 + (pw5*se*u1 + pw6*cpu1)*q1;
    mv2 += pw4*ve2*q0 + (pw5*se*u2 + pw6*cpu2)*q1;
    mpv0 += pw7*pve0*q0 + (pw8*pse*u0 + pw9*cvu0)*q1;
    mpv1 += pw7*pve1*q0 + (pw8*pse*u1 + pw9*cvu1)*q1;
    mpv2 += pw7*pve2*q0 + (pw8*pse*u2 + pw9*cvu2)*q1;
  }
  size_t db = (size_t)n*F_, dvb = (size_t)n*3*F_;
  ys[db+f] = ms;
  yps[db+f] = mps;
  yv[dvb+f] = mv0;   yv[dvb+F_+f] = mv1;   yv[dvb+2*F_+f] = mv2;
  ypv[dvb+f] = mpv0; ypv[dvb+F_+f] = mpv1; ypv[dvb+2*F_+f] = mpv2;
}

// ---------------- forward node MLP: warp-per-node, LDS-staged b128 broadcasts ----------------
__global__ __launch_bounds__(256) void node_fwd_kernel(
    float* __restrict__ s, float* __restrict__ v, float* __restrict__ ps, float* __restrict__ pv,
    const float* __restrict__ ys, const float* __restrict__ yv,
    const float* __restrict__ yps, const float* __restrict__ ypv,
    const float* __restrict__ W1, const float* __restrict__ b1v,
    const float* __restrict__ W2, const float* __restrict__ b2v,
    float* __restrict__ a_s, float* __restrict__ a_v,
    float* __restrict__ a_ps, float* __restrict__ a_pv) {
  __shared__ float stage[8][8][32];
  int tid = threadIdx.x;
  int w = tid >> 5, f = tid & 31;
  int n = blockIdx.x * 8 + w;
  size_t ib = (size_t)n*F_ + f;
  size_t vb = (size_t)n*3*F_ + f;
  const int FF = F_*F_;
  stage[w][0][f] = s[ib]       + ys[ib];
  stage[w][1][f] = v[vb]       + yv[vb];
  stage[w][2][f] = v[vb+F_]    + yv[vb+F_];
  stage[w][3][f] = v[vb+2*F_]  + yv[vb+2*F_];
  stage[w][4][f] = ps[ib]      + yps[ib];
  stage[w][5][f] = pv[vb]      + ypv[vb];
  stage[w][6][f] = pv[vb+F_]   + ypv[vb+F_];
  stage[w][7][f] = pv[vb+2*F_] + ypv[vb+2*F_];
  __syncthreads();
  const float* W1s = W1; const float* W1v = W1 + FF;
  const float* W1p = W1 + 2*FF; const float* W1q = W1 + 3*FF;
  float a0 = b1v[f], a1=0.f, a2=0.f, a3=0.f, a4=0.f, a5=0.f, a6=0.f, a7=0.f;
#pragma unroll
  for (int q = 0; q < 8; ++q) {
    float4 c0=((const float4*)stage[w][0])[q], c1=((const float4*)stage[w][1])[q];
    float4 c2=((const float4*)stage[w][2])[q], c3=((const float4*)stage[w][3])[q];
    float4 c4=((const float4*)stage[w][4])[q], c5=((const float4*)stage[w][5])[q];
    float4 c6=((const float4*)stage[w][6])[q], c7=((const float4*)stage[w][7])[q];
    float e0[4]={c0.x,c0.y,c0.z,c0.w}, e1[4]={c1.x,c1.y,c1.z,c1.w};
    float e2[4]={c2.x,c2.y,c2.z,c2.w}, e3[4]={c3.x,c3.y,c3.z,c3.w};
    float e4[4]={c4.x,c4.y,c4.z,c4.w}, e5[4]={c5.x,c5.y,c5.z,c5.w};
    float e6[4]={c6.x,c6.y,c6.z,c6.w}, e7[4]={c7.x,c7.y,c7.z,c7.w};
#pragma unroll
    for (int j = 0; j < 4; ++j) {
      int fp = 4*q + j;
      float ws_ = W1s[fp*F_+f], wv_ = W1v[fp*F_+f], wp_ = W1p[fp*F_+f], wq_ = W1q[fp*F_+f];
      a0 = fmaf(e0[j], ws_, a0);
      a1 = fmaf(e1[j], wv_, a1);
      a2 = fmaf(e2[j], wv_, a2);
      a3 = fmaf(e3[j], wv_, a3);
      a4 = fmaf(e4[j], wp_, a4);
      a5 = fmaf(e5[j], wq_, a5);
      a6 = fmaf(e6[j], wq_, a6);
      a7 = fmaf(e7[j], wq_, a7);
    }
  }
  a_s[ib]=a0; a_v[vb]=a1; a_v[vb+F_]=a2; a_v[vb+2*F_]=a3;
  a_ps[ib]=a4; a_pv[vb]=a5; a_pv[vb+F_]=a6; a_pv[vb+2*F_]=a7;
  float g = sigm(a0);
  __syncthreads();
  stage[w][0][f]=a0*g; stage[w][1][f]=a1*g; stage[w][2][f]=a2*g; stage[w][3][f]=a3*g;
  stage[w][4][f]=a4*g; stage[w][5][f]=a5*g; stage[w][6][f]=a6*g; stage[w][7][f]=a7*g;
  __syncthreads();
  const float* W2s = W2; const float* W2v = W2 + FF;
  const float* W2p = W2 + 2*FF; const float* W2q = W2 + 3*FF;
  float o0 = b2v[f], o1=0.f, o2=0.f, o3=0.f, o4=0.f, o5=0.f, o6=0.f, o7=0.f;
#pragma unroll
  for (int q = 0; q < 8; ++q) {
    float4 c0=((const float4*)stage[w][0])[q], c1=((const float4*)stage[w][1])[q];
    float4 c2=((const float4*)stage[w][2])[q], c3=((const float4*)stage[w][3])[q];
    float4 c4=((const float4*)stage[w][4])[q], c5=((const float4*)stage[w][5])[q];
    float4 c6=((const float4*)stage[w][6])[q], c7=((const float4*)stage[w][7])[q];
    float e0[4]={c0.x,c0.y,c0.z,c0.w}, e1[4]={c1.x,c1.y,c1.z,c1.w};
    float e2[4]={c2.x,c2.y,c2.z,c2.w}, e3[4]={c3.x,c3.y,c3.z,c3.w};
    float e4[4]={c4.x,c4.y,c4.z,c4.w}, e5[4]={c5.x,c5.y,c5.z,c5.w};
    float e6[4]={c6.x,c6.y,c6.z,c6.w}, e7[4]={c7.x,c7.y,c7.z,c7.w};
#pragma unroll
    for (int j = 0; j < 4; ++j) {
      int fp = 4*q + j;
      float ws_ = W2s[fp*F_+f], wv_ = W2v[fp*F_+f], wp_ = W2p[fp*F_+f], wq_ = W2q[fp*F_+f];
      o0 = fmaf(e0[j], ws_, o0);
      o1 = fmaf(e1[j], wv_, o1);
      o2 = fmaf(e2[j], wv_, o2);
      o3 = fmaf(e3[j], wv_, o3);
      o4 = fmaf(e4[j], wp_, o4);
      o5 = fmaf(e5[j], wq_, o5);
      o6 = fmaf(e6[j], wq_, o6);
      o7 = fmaf(e7[j], wq_, o7);
    }
  }
  s[ib] += o0;
  v[vb] += o1; v[vb+F_] += o2; v[vb+2*F_] += o3;
  ps[ib] += o4;
  pv[vb] += o5; pv[vb+F_] += o6; pv[vb+2*F_] += o7;
}

// ---------------- forward last (scalar) pass ----------------
__global__ __launch_bounds__(256) void edge_fwd_last_csr(
    const int* __restrict__ ord_d,
    const int* __restrict__ dst_off, const int* __restrict__ dst_perm,
    const int* __restrict__ src,
    const float* __restrict__ rd, const float* __restrict__ u3,
    const float* __restrict__ Wb0, const float* __restrict__ Wb1, const float* __restrict__ pwl,
    const float* __restrict__ s, const float* __restrict__ v, float* __restrict__ ys) {
  int gid = blockIdx.x * 256 + threadIdx.x;
  int n = ord_d[gid >> 5];
  int f = gid & 31;
  float wb0[K_], wb1[K_];
#pragma unroll
  for (int k = 0; k < K_; ++k) { wb0[k] = Wb0[k*F_+f]; wb1[k] = Wb1[k*F_+f]; }
  float p0 = pwl[f], p1 = pwl[F_+f];
  float m = 0.f;
  int j0 = dst_off[n], j1 = dst_off[n+1];
  for (int j = j0; j < j1; ++j) {
    int e = dst_perm[j];
    int ns = src[e];
    float radl = (f < K_) ? rd[(size_t)e*32 + f] : 0.f;
    float q0 = 0.f, q1 = 0.f;
#pragma unroll
    for (int k = 0; k < K_; ++k) {
      float rk = __shfl(radl, k, 32);
      q0 += rk * wb0[k];
      q1 += rk * wb1[k];
    }
    float u0 = u3[(size_t)e*3+0], u1 = u3[(size_t)e*3+1], u2 = u3[(size_t)e*3+2];
    float se = s[(size_t)ns*F_+f];
    size_t vb = (size_t)ns*3*F_;
    float vu = v[vb+f]*u0 + v[vb+F_+f]*u1 + v[vb+2*F_+f]*u2;
    m += p0*se*q0 + p1*vu*q1;
  }
  ys[(size_t)n*F_+f] = m;
}

__global__ __launch_bounds__(256) void node_fwd_last_kernel(
    float* __restrict__ s, const float* __restrict__ ys,
    const float* __restrict__ W1, const float* __restrict__ b1v,
    const float* __restrict__ W2, const float* __restrict__ b2v,
    float* __restrict__ a_l, const float* __restrict__ w_out,
    const float* __restrict__ ebias, const int* __restrict__ Z,
    const int* __restrict__ bseg, float* __restrict__ energy) {
  __shared__ float stage[8][32];
  __shared__ float bins[B_];
  int tid = threadIdx.x;
  if (tid < B_) bins[tid] = 0.f;
  int w = tid >> 5, f = tid & 31;
  int n = blockIdx.x * 8 + w;
  size_t ib = (size_t)n*F_ + f;
  stage[w][f] = s[ib] + ys[ib];
  __syncthreads();
  float a = b1v[f];
#pragma unroll
  for (int q = 0; q < 8; ++q) {
    float4 c = ((const float4*)stage[w])[q];
    float e[4] = {c.x,c.y,c.z,c.w};
#pragma unroll
    for (int j = 0; j < 4; ++j) a = fmaf(e[j], W1[(4*q+j)*F_+f], a);
  }
  a_l[ib] = a;
  float g = sigm(a);
  __syncthreads();
  stage[w][f] = a*g;
  __syncthreads();
  float o = b2v[f];
#pragma unroll
  for (int q = 0; q < 8; ++q) {
    float4 c = ((const float4*)stage[w])[q];
    float e[4] = {c.x,c.y,c.z,c.w};
#pragma unroll
    for (int j = 0; j < 4; ++j) o = fmaf(e[j], W2[(4*q+j)*F_+f], o);
  }
  float sn = s[ib] + o;
  s[ib] = sn;
  float c = sn * w_out[f];
#pragma unroll
  for (int off = 16; off > 0; off >>= 1) c += __shfl_xor(c, off, 32);
  if (f == 0) atomicAdd(&bins[bseg[n]], c + ebias[Z[n]]);
  __syncthreads();
  if (tid < B_) atomicAdd(&energy[tid], bins[tid]);
}

// ---------------- backward last (scalar) pass ----------------
__global__ __launch_bounds__(256) void b1_last_kernel(
    float* __restrict__ s, const float* __restrict__ a_l,
    const float* __restrict__ W1, const float* __restrict__ W2, const float* __restrict__ b2v,
    float* __restrict__ Gs, float* __restrict__ ys) {
  __shared__ float stage[8][32];
  int tid = threadIdx.x;
  int w = tid >> 5, f = tid & 31;
  int n = blockIdx.x * 8 + w;
  size_t ib = (size_t)n*F_ + f;
  float a = a_l[ib];
  float g = sigm(a);
  stage[w][f] = a*g;
  __syncthreads();
  float o = b2v[f];
#pragma unroll
  for (int q = 0; q < 8; ++q) {
    float4 c = ((const float4*)stage[w])[q];
    float e[4] = {c.x,c.y,c.z,c.w};
#pragma unroll
    for (int j = 0; j < 4; ++j) o = fmaf(e[j], W2[(4*q+j)*F_+f], o);
  }
  s[ib] -= o;                         // reconstruct s_4
  float G = Gs[ib];
  __syncthreads();
  stage[w][f] = G;
  __syncthreads();
  float gh = 0.f;
#pragma unroll
  for (int q = 0; q < 8; ++q) {
    float4 c = ((const float4*)stage[w])[q];
    float4 wt = ((const float4*)(W2 + f*F_))[q];
    float e[4] = {c.x,c.y,c.z,c.w};
    float ww[4] = {wt.x,wt.y,wt.z,wt.w};
#pragma unroll
    for (int j = 0; j < 4; ++j) gh = fmaf(e[j], ww[j], gh);
  }
  float ga = gh * (g + a*g*(1.f - g));
  __syncthreads();
  stage[w][f] = ga;
  __syncthreads();
  float gy = 0.f;
#pragma unroll
  for (int q = 0; q < 8; ++q) {
    float4 c = ((const float4*)stage[w])[q];
    float4 wt = ((const float4*)(W1 + f*F_))[q];
    float e[4] = {c.x,c.y,c.z,c.w};
    float ww[4] = {wt.x,wt.y,wt.z,wt.w};
#pragma unroll
    for (int j = 0; j < 4; ++j) gy = fmaf(e[j], ww[j], gy);
  }
  ys[ib] = gy;
  Gs[ib] = G + gy;
}

// merged backward last edge pass: 32 lanes per SRC node
__global__ __launch_bounds__(256) void b2m_last_kernel(
    const int* __restrict__ ord_s,
    const int* __restrict__ src_off, const int* __restrict__ src_perm,
    const int* __restrict__ dst,
    const float* __restrict__ rd, const float* __restrict__ u3,
    const float* __restrict__ Wb0, const float* __restrict__ Wb1, const float* __restrict__ pwl,
    const float* __restrict__ s, const float* __restrict__ v, const float* __restrict__ ysg,
    float* __restrict__ Gs, float* __restrict__ Gv,
    float* __restrict__ grad_r, float* __restrict__ grad_u) {
  int gid = blockIdx.x * 256 + threadIdx.x;
  int n = ord_s[gid >> 5];
  int f = gid & 31;
  float wb0[K_], wb1[K_];
#pragma unroll
  for (int k = 0; k < K_; ++k) { wb0[k] = Wb0[k*F_+f]; wb1[k] = Wb1[k*F_+f]; }
  float p0 = pwl[f], p1 = pwl[F_+f];
  size_t sb = (size_t)n*F_, svb = (size_t)n*3*F_;
  float se = s[sb+f];
  float ve0 = v[svb+f], ve1 = v[svb+F_+f], ve2 = v[svb+2*F_+f];
  float ags = 0.f, agv0 = 0.f, agv1 = 0.f, agv2 = 0.f;
  int j0 = src_off[n], j1 = src_off[n+1];
  for (int j = j0; j < j1; ++j) {
    int e = src_perm[j];
    int nd = dst[e];
    float rdl = rd[(size_t)e*32 + f];   // f<16: rad_f ; f>=16: drad_{f-16}
    float q0 = 0.f, q1 = 0.f, w0 = 0.f, w1 = 0.f;
#pragma unroll
    for (int k = 0; k < K_; ++k) {
      float rk = __shfl(rdl, k, 32);
      float dk = __shfl(rdl, k + 16, 32);
      q0 += rk * wb0[k]; q1 += rk * wb1[k];
      w0 += dk * wb0[k]; w1 += dk * wb1[k];
    }
    float u0 = u3[(size_t)e*3+0], u1 = u3[(size_t)e*3+1], u2 = u3[(size_t)e*3+2];
    float gm = ysg[(size_t)nd*F_+f];
    ags += p0*q0*gm;
    float t1 = p1*q1*gm;
    agv0 += t1*u0; agv1 += t1*u1; agv2 += t1*u2;
    float vu = ve0*u0 + ve1*u1 + ve2*u2;
    float gq0 = p0*se*gm;
    float gq1 = p1*vu*gm;
    float grl = gq0*w0 + gq1*w1;
    float gu0 = t1*ve0, gu1 = t1*ve1, gu2 = t1*ve2;
#pragma unroll
    for (int off = 16; off > 0; off >>= 1) {
      grl += __shfl_xor(grl, off, 32);
      gu0 += __shfl_xor(gu0, off, 32);
      gu1 += __shfl_xor(gu1, off, 32);
      gu2 += __shfl_xor(gu2, off, 32);
    }
    if (f == 0) grad_r[e] = grl;                  // first writer of the backward chain
    if (f < 3) grad_u[(size_t)e*3+f] = (f==0 ? gu0 : (f==1 ? gu1 : gu2));
  }
  Gs[sb+f] += ags;
  Gv[svb+f] += agv0; Gv[svb+F_+f] += agv1; Gv[svb+2*F_+f] += agv2;
}

// ---------------- backward node MLP: warp-per-node, LDS-staged b128 broadcasts ----------------
__global__ __launch_bounds__(256) void b1_kernel(
    float* __restrict__ s, float* __restrict__ v, float* __restrict__ ps, float* __restrict__ pv,
    const float* __restrict__ a_s, const float* __restrict__ a_v,
    const float* __restrict__ a_ps, const float* __restrict__ a_pv,
    const float* __restrict__ W1, const float* __restrict__ W2, const float* __restrict__ b2v,
    float* __restrict__ Gs, float* __restrict__ Gv, float* __restrict__ Gps, float* __restrict__ Gpv,
    float* __restrict__ ys, float* __restrict__ yv, float* __restrict__ yps, float* __restrict__ ypv) {
  __shared__ float stage[8][8][32];
  int tid = threadIdx.x;
  int w = tid >> 5, f = tid & 31;
  int n = blockIdx.x * 8 + w;
  size_t ib = (size_t)n*F_ + f;
  size_t vb = (size_t)n*3*F_ + f;
  const int FF = F_*F_;
  float a0=a_s[ib], a1=a_v[vb], a2=a_v[vb+F_], a3=a_v[vb+2*F_];
  float a4=a_ps[ib], a5=a_pv[vb], a6=a_pv[vb+F_], a7=a_pv[vb+2*F_];
  float g = sigm(a0), gp = g*(1.f-g);
  stage[w][0][f]=a0*g; stage[w][1][f]=a1*g; stage[w][2][f]=a2*g; stage[w][3][f]=a3*g;
  stage[w][4][f]=a4*g; stage[w][5][f]=a5*g; stage[w][6][f]=a6*g; stage[w][7][f]=a7*g;
  __syncthreads();
  const float* W1s = W1; const float* W1v = W1 + FF;
  const float* W1p = W1 + 2*FF; const float* W1q = W1 + 3*FF;
  const float* W2s = W2; const float* W2v = W2 + FF;
  const float* W2p = W2 + 2*FF; const float* W2q = W2 + 3*FF;
  // loop1: recompute forward outputs o_c = b2 + W2 @ h  (broadcast h from LDS)
  float o0 = b2v[f], o1=0.f, o2=0.f, o3=0.f, o4=0.f, o5=0.f, o6=0.f, o7=0.f;
#pragma unroll
  for (int q = 0; q < 8; ++q) {
    float4 c0=((const float4*)stage[w][0])[q], c1=((const float4*)stage[w][1])[q];
    float4 c2=((const float4*)stage[w][2])[q], c3=((const float4*)stage[w][3])[q];
    float4 c4=((const float4*)stage[w][4])[q], c5=((const float4*)stage[w][5])[q];
    float4 c6=((const float4*)stage[w][6])[q], c7=((const float4*)stage[w][7])[q];
    float e0[4]={c0.x,c0.y,c0.z,c0.w}, e1[4]={c1.x,c1.y,c1.z,c1.w};
    float e2[4]={c2.x,c2.y,c2.z,c2.w}, e3[4]={c3.x,c3.y,c3.z,c3.w};
    float e4[4]={c4.x,c4.y,c4.z,c4.w}, e5[4]={c5.x,c5.y,c5.z,c5.w};
    float e6[4]={c6.x,c6.y,c6.z,c6.w}, e7[4]={c7.x,c7.y,c7.z,c7.w};
#pragma unroll
    for (int j = 0; j < 4; ++j) {
      int fp = 4*q + j;
      float ws_ = W2s[fp*F_+f], wv_ = W2v[fp*F_+f], wp_ = W2p[fp*F_+f], wq_ = W2q[fp*F_+f];
      o0 = fmaf(e0[j], ws_, o0);
      o1 = fmaf(e1[j], wv_, o1);
      o2 = fmaf(e2[j], wv_, o2);
      o3 = fmaf(e3[j], wv_, o3);
      o4 = fmaf(e4[j], wp_, o4);
      o5 = fmaf(e5[j], wq_, o5);
      o6 = fmaf(e6[j], wq_, o6);
      o7 = fmaf(e7[j], wq_, o7);
    }
  }
  s[ib] -= o0;
  v[vb] -= o1; v[vb+F_] -= o2; v[vb+2*F_] -= o3;
  ps[ib] -= o4;
  pv[vb] -= o5; pv[vb+F_] -= o6; pv[vb+2*F_] -= o7;
  float G0=Gs[ib], G1=Gv[vb], G2=Gv[vb+F_], G3=Gv[vb+2*F_];
  float G4=Gps[ib], G5=Gpv[vb], G6=Gpv[vb+F_], G7=Gpv[vb+2*F_];
  __syncthreads();
  stage[w][0][f]=G0; stage[w][1][f]=G1; stage[w][2][f]=G2; stage[w][3][f]=G3;
  stage[w][4][f]=G4; stage[w][5][f]=G5; stage[w][6][f]=G6; stage[w][7][f]=G7;
  __syncthreads();
  // loop2: gh_c[f] = sum_fp G_c[fp] * W2t[f][fp]   (float4 weight rows)
  float h0=0.f,h1=0.f,h2=0.f,h3=0.f,h4=0.f,h5=0.f,h6=0.f,h7=0.f;
#pragma unroll
  for (int q = 0; q < 8; ++q) {
    float4 c0=((const float4*)stage[w][0])[q], c1=((const float4*)stage[w][1])[q];
    float4 c2=((const float4*)stage[w][2])[q], c3=((const float4*)stage[w][3])[q];
    float4 c4=((const float4*)stage[w][4])[q], c5=((const float4*)stage[w][5])[q];
    float4 c6=((const float4*)stage[w][6])[q], c7=((const float4*)stage[w][7])[q];
    float4 ws4=((const float4*)(W2s + f*F_))[q];
    float4 wv4=((const float4*)(W2v + f*F_))[q];
    float4 wp4=((const float4*)(W2p + f*F_))[q];
    float4 wq4=((const float4*)(W2q + f*F_))[q];
    float e0[4]={c0.x,c0.y,c0.z,c0.w}, e1[4]={c1.x,c1.y,c1.z,c1.w};
    float e2[4]={c2.x,c2.y,c2.z,c2.w}, e3[4]={c3.x,c3.y,c3.z,c3.w};
    float e4[4]={c4.x,c4.y,c4.z,c4.w}, e5[4]={c5.x,c5.y,c5.z,c5.w};
    float e6[4]={c6.x,c6.y,c6.z,c6.w}, e7[4]={c7.x,c7.y,c7.z,c7.w};
    float ws_[4]={ws4.x,ws4.y,ws4.z,ws4.w}, wv_[4]={wv4.x,wv4.y,wv4.z,wv4.w};
    float wp_[4]={wp4.x,wp4.y,wp4.z,wp4.w}, wq_[4]={wq4.x,wq4.y,wq4.z,wq4.w};
#pragma unroll
    for (int j = 0; j < 4; ++j) {
      h0 = fmaf(e0[j], ws_[j], h0);
      h1 = fmaf(e1[j], wv_[j], h1);
      h2 = fmaf(e2[j], wv_[j], h2);
      h3 = fmaf(e3[j], wv_[j], h3);
      h4 = fmaf(e4[j], wp_[j], h4);
      h5 = fmaf(e5[j], wq_[j], h5);
      h6 = fmaf(e6[j], wq_[j], h6);
      h7 = fmaf(e7[j], wq_[j], h7);
    }
  }
  float dot = h0*a0 + h1*a1 + h2*a2 + h3*a3 + h4*a4 + h5*a5 + h6*a6 + h7*a7;
  float ga0 = h0*g + dot*gp;
  float ga1 = h1*g, ga2 = h2*g, ga3 = h3*g, ga4 = h4*g;
  float ga5 = h5*g, ga6 = h6*g, ga7 = h7*g;
  __syncthreads();
  stage[w][0][f]=ga0; stage[w][1][f]=ga1; stage[w][2][f]=ga2; stage[w][3][f]=ga3;
  stage[w][4][f]=ga4; stage[w][5][f]=ga5; stage[w][6][f]=ga6; stage[w][7][f]=ga7;
  __syncthreads();
  // loop3: gy_c[f] = sum_fp ga_c[fp] * W1t[f][fp]
  float y0=0.f,y1=0.f,y2=0.f,y3=0.f,y4=0.f,y5=0.f,y6=0.f,y7=0.f;
#pragma unroll
  for (int q = 0; q < 8; ++q) {
    float4 c0=((const float4*)stage[w][0])[q], c1=((const float4*)stage[w][1])[q];
    float4 c2=((const float4*)stage[w][2])[q], c3=((const float4*)stage[w][3])[q];
    float4 c4=((const float4*)stage[w][4])[q], c5=((const float4*)stage[w][5])[q];
    float4 c6=((const float4*)stage[w][6])[q], c7=((const float4*)stage[w][7])[q];
    float4 ws4=((const float4*)(W1s + f*F_))[q];
    float4 wv4=((const float4*)(W1v + f*F_))[q];
    float4 wp4=((const float4*)(W1p + f*F_))[q];
    float4 wq4=((const float4*)(W1q + f*F_))[q];
    float e0[4]={c0.x,c0.y,c0.z,c0.w}, e1[4]={c1.x,c1.y,c1.z,c1.w};
    float e2[4]={c2.x,c2.y,c2.z,c2.w}, e3[4]={c3.x,c3.y,c3.z,c3.w};
    float e4[4]={c4.x,c4.y,c4.z,c4.w}, e5[4]={c5.x,c5.y,c5.z,c5.w};
    float e6[4]={c6.x,c6.y,c6.z,c6.w}, e7[4]={c7.x,c7.y,c7.z,c7.w};
    float ws_[4]={ws4.x,ws4.y,ws4.z,ws4.w}, wv_[4]={wv4.x,wv4.y,wv4.z,wv4.w};
    float wp_[4]={wp4.x,wp4.y,wp4.z,wp4.w}, wq_[4]={wq4.x,wq4.y,wq4.z,wq4.w};
#pragma unroll
    for (int j = 0; j < 4; ++j) {
      y0 = fmaf(e0[j], ws_[j], y0);
      y1 = fmaf(e1[j], wv_[j], y1);
      y2 = fmaf(e2[j], wv_[j], y2);
      y3 = fmaf(e3[j], wv_[j], y3);
      y4 = fmaf(e4[j], wp_[j], y4);
      y5 = fmaf(e5[j], wq_[j], y5);
      y6 = fmaf(e6[j], wq_[j], y6);
      y7 = fmaf(e7[j], wq_[j], y7);
    }
  }
  ys[ib]=y0; yv[vb]=y1; yv[vb+F_]=y2; yv[vb+2*F_]=y3;
  yps[ib]=y4; ypv[vb]=y5; ypv[vb+F_]=y6; ypv[vb+2*F_]=y7;
  Gs[ib]=G0+y0; Gv[vb]=G1+y1; Gv[vb+F_]=G2+y2; Gv[vb+2*F_]=G3+y3;
  Gps[ib]=G4+y4; Gpv[vb]=G5+y5; Gpv[vb+F_]=G6+y6; Gpv[vb+2*F_]=G7+y7;
}

// ---------------- merged backward edge pass: 32 lanes per SRC node ----------------
__global__ __launch_bounds__(256) void b2m_kernel(
    const int* __restrict__ ord_s,
    const int* __restrict__ src_off, const int* __restrict__ src_perm,
    const int* __restrict__ dst,
    const float* __restrict__ rd, const float* __restrict__ u3,
    const float* __restrict__ Wb0, const float* __restrict__ Wb1, const float* __restrict__ pw,
    const float* __restrict__ s, const float* __restrict__ v,
    const float* __restrict__ ps, const float* __restrict__ pv,
    const float* __restrict__ ys, const float* __restrict__ yv,
    const float* __restrict__ yps, const float* __restrict__ ypv,
    float* __restrict__ Gs, float* __restrict__ Gv, float* __restrict__ Gps, float* __restrict__ Gpv,
    float* __restrict__ grad_r, float* __restrict__ grad_u) {
  int gid = blockIdx.x * 256 + threadIdx.x;
  int n = ord_s[gid >> 5];
  int f = gid & 31;
  float wb0[K_], wb1[K_];
#pragma unroll
  for (int k = 0; k < K_; ++k) { wb0[k] = Wb0[k*F_+f]; wb1[k] = Wb1[k*F_+f]; }
  float pw0=pw[f],      pw1=pw[F_+f],   pw2=pw[2*F_+f], pw3=pw[3*F_+f], pw4=pw[4*F_+f];
  float pw5=pw[5*F_+f], pw6=pw[6*F_+f], pw7=pw[7*F_+f], pw8=pw[8*F_+f], pw9=pw[9*F_+f];
  size_t sb = (size_t)n*F_, svb = (size_t)n*3*F_;
  float se = s[sb+f], pse = ps[sb+f];
  float ve0 = v[svb+f], ve1 = v[svb+F_+f], ve2 = v[svb+2*F_+f];
  float pve0 = pv[svb+f], pve1 = pv[svb+F_+f], pve2 = pv[svb+2*F_+f];
  float ase=0.f, apse=0.f;
  float ave0=0.f, ave1=0.f, ave2=0.f, apve0=0.f, apve1=0.f, apve2=0.f;
  int j0 = src_off[n], j1 = src_off[n+1];
  for (int j = j0; j < j1; ++j) {
    int e = src_perm[j];
    int nd = dst[e];
    float rdl = rd[(size_t)e*32 + f];
    float q0 = 0.f, q1 = 0.f, w0 = 0.f, w1 = 0.f;
#pragma unroll
    for (int k = 0; k < K_; ++k) {
      float rk = __shfl(rdl, k, 32);
      float dk = __shfl(rdl, k + 16, 32);
      q0 += rk * wb0[k]; q1 += rk * wb1[k];
      w0 += dk * wb0[k]; w1 += dk * wb1[k];
    }
    float u0 = u3[(size_t)e*3+0], u1 = u3[(size_t)e*3+1], u2 = u3[(size_t)e*3+2];
    size_t db = (size_t)nd*F_, dvb = (size_t)nd*3*F_;
    float gms = ys[db+f];
    float gmv0 = yv[dvb+f], gmv1 = yv[dvb+F_+f], gmv2 = yv[dvb+2*F_+f];
    float gmps = yps[db+f];
    float gmpv0 = ypv[dvb+f], gmpv1 = ypv[dvb+F_+f], gmpv2 = ypv[dvb+2*F_+f];
    float udgmv  = u0*gmv0 + u1*gmv1 + u2*gmv2;
    float udgmpv = u0*gmpv0 + u1*gmpv1 + u2*gmpv2;
    float uxgmpv0 = u1*gmpv2 - u2*gmpv1, uxgmpv1 = u2*gmpv0 - u0*gmpv2, uxgmpv2 = u0*gmpv1 - u1*gmpv0;
    float uxgmv0  = u1*gmv2 - u2*gmv1,   uxgmv1  = u2*gmv0 - u0*gmv2,   uxgmv2  = u0*gmv1 - u1*gmv0;
    // own-state (source) grads — accumulate locally
    ase  += pw0*q0*gms  + pw5*q1*udgmv;
    apse += pw2*q0*gmps + pw8*q1*udgmpv;
    ave0 += pw1*u0*q1*gms + pw4*q0*gmv0 + pw9*q1*uxgmpv0;
    ave1 += pw1*u1*q1*gms + pw4*q0*gmv1 + pw9*q1*uxgmpv1;
    ave2 += pw1*u2*q1*gms + pw4*q0*gmv2 + pw9*q1*uxgmpv2;
    apve0 += pw3*u0*q1*gmps + pw7*q0*gmpv0 + pw6*q1*uxgmv0;
    apve1 += pw3*u1*q1*gmps + pw7*q0*gmpv1 + pw6*q1*uxgmv1;
    apve2 += pw3*u2*q1*gmps + pw7*q0*gmpv2 + pw6*q1*uxgmv2;
    // basis grads (need own state x dst grads)
    float vu  = ve0*u0 + ve1*u1 + ve2*u2;
    float pvu = pve0*u0 + pve1*u1 + pve2*u2;
    float cpu0 = pve1*u2 - pve2*u1, cpu1 = pve2*u0 - pve0*u2, cpu2 = pve0*u1 - pve1*u0;
    float cvu0 = ve1*u2 - ve2*u1,  cvu1 = ve2*u0 - ve0*u2,  cvu2 = ve0*u1 - ve1*u0;
    float gq0 = pw0*se*gms + pw2*pse*gmps
              + pw4*(ve0*gmv0 + ve1*gmv1 + ve2*gmv2)
              + pw7*(pve0*gmpv0 + pve1*gmpv1 + pve2*gmpv2);
    float gq1 = pw1*vu*gms + pw3*pvu*gmps + pw5*se*udgmv
              + pw6*(cpu0*gmv0 + cpu1*gmv1 + cpu2*gmv2)
              + pw8*pse*udgmpv
              + pw9*(cvu0*gmpv0 + cvu1*gmpv1 + cvu2*gmpv2);
    float grl = gq0*w0 + gq1*w1;   // dL/dr contribution (projected through drad)
    float gmvxpve0 = gmv1*pve2 - gmv2*pve1, gmvxpve1 = gmv2*pve0 - gmv0*pve2, gmvxpve2 = gmv0*pve1 - gmv1*pve0;
    float gmpvxve0 = gmpv1*ve2 - gmpv2*ve1, gmpvxve1 = gmpv2*ve0 - gmpv0*ve2, gmpvxve2 = gmpv0*ve1 - gmpv1*ve0;
    float gu0 = q1*(pw1*gms*ve0 + pw3*gmps*pve0 + pw5*se*gmv0 + pw6*gmvxpve0 + pw8*pse*gmpv0 + pw9*gmpvxve0);
    float gu1 = q1*(pw1*gms*ve1 + pw3*gmps*pve1 + pw5*se*gmv1 + pw6*gmvxpve1 + pw8*pse*gmpv1 + pw9*gmpvxve1);
    float gu2 = q1*(pw1*gms*ve2 + pw3*gmps*pve2 + pw5*se*gmv2 + pw6*gmvxpve2 + pw8*pse*gmpv2 + pw9*gmpvxve2);
#pragma unroll
    for (int off = 16; off > 0; off >>= 1) {
      grl += __shfl_xor(grl, off, 32);
      gu0 += __shfl_xor(gu0, off, 32);
      gu1 += __shfl_xor(gu1, off, 32);
      gu2 += __shfl_xor(gu2, off, 32);
    }
    if (f == 0) grad_r[e] += grl;
    if (f < 3) grad_u[(size_t)e*3+f] += (f==0 ? gu0 : (f==1 ? gu1 : gu2));
  }
  Gs[sb+f]  += ase;
  Gps[sb+f] += apse;
  Gv[svb+f] += ave0;  Gv[svb+F_+f] += ave1;  Gv[svb+2*F_+f] += ave2;
  Gpv[svb+f] += apve0; Gpv[svb+F_+f] += apve1; Gpv[svb+2*F_+f] += apve2;
}

// ---------------- basis backward: (grad_r, grad_u) -> forces ----------------
__global__ void basis_bwd_kernel(const int* __restrict__ dst, const int* __restrict__ src,
                                 const float* __restrict__ rr, const float* __restrict__ u3,
                                 const float* __restrict__ grad_r, const float* __restrict__ grad_u,
                                 float* __restrict__ forces) {
  int e = blockIdx.x * blockDim.x + threadIdx.x;
  if (e >= E_) return;
  float r = rr[e];
  float u0 = u3[(size_t)e*3+0], u1 = u3[(size_t)e*3+1], u2 = u3[(size_t)e*3+2];
  float gr = grad_r[e];
  float g0 = grad_u[(size_t)e*3+0], g1 = grad_u[(size_t)e*3+1], g2 = grad_u[(size_t)e*3+2];
  float gdu = g0*u0 + g1*u1 + g2*u2;
  float invr = 1.f / r;
  float gd0 = gr*u0 + (g0 - gdu*u0)*invr;
  float gd1 = gr*u1 + (g1 - gdu*u1)*invr;
  float gd2 = gr*u2 + (g2 - gdu*u2)*invr;
  int ns = src[e], nd = dst[e];
  atomicAdd(&forces[(size_t)ns*3+0], gd0);
  atomicAdd(&forces[(size_t)ns*3+1], gd1);
  atomicAdd(&forces[(size_t)ns*3+2], gd2);
  atomicAdd(&forces[(size_t)nd*3+0], -gd0);
  atomicAdd(&forces[(size_t)nd*3+1], -gd1);
  atomicAdd(&forces[(size_t)nd*3+2], -gd2);
}

// ---------------- host launcher ----------------
extern "C" void kernel_launch(void* const* d_in, const int* in_sizes, int n_in,
                              void* d_out, int out_size, void* d_ws, size_t ws_size,
                              hipStream_t stream) {
  const int*   Z     = (const int*)d_in[0];
  const float* pos   = (const float*)d_in[1];
  const int*   dst   = (const int*)d_in[2];
  const int*   src   = (const int*)d_in[3];
  const int*   bseg  = (const int*)d_in[4];
  const float* embed = (const float*)d_in[6];
  const float* Wb0   = (const float*)d_in[7];
  const float* Wb1   = (const float*)d_in[8];
  const float* pw    = (const float*)d_in[9];
  const float* Wd1   = (const float*)d_in[10];
  const float* bd1   = (const float*)d_in[11];
  const float* Wd2   = (const float*)d_in[12];
  const float* bd2   = (const float*)d_in[13];
  const float* Wb0l  = (const float*)d_in[14];
  const float* Wb1l  = (const float*)d_in[15];
  const float* pwl   = (const float*)d_in[16];
  const float* Wd1l  = (const float*)d_in[17];
  const float* bd1l  = (const float*)d_in[18];
  const float* Wd2l  = (const float*)d_in[19];
  const float* bd2l  = (const float*)d_in[20];
  const float* w_out = (const float*)d_in[21];
  const float* ebias = (const float*)d_in[22];

  float* out = (float*)d_out;
  float* energy = out;          // (B,)
  float* forces = out + B_;     // (N,3)

  float* ws = nullptr;
  (void)hipGetSymbolAddress((void**)&ws, HIP_SYMBOL(g_ws));

  const size_t NF = (size_t)N_ * F_;
  const size_t NV = (size_t)N_ * 3 * F_;
  float* rd       = ws;                       // E*32 (rad | drad)
  float* u3       = rd + (size_t)E_*32;       // E*3
  float* rr       = u3 + (size_t)E_*3;        // E
  float* s        = rr + E_;                  // N*F
  float* v        = s + NF;                   // N*3F
  float* ps       = v + NV;                   // N*F
  float* pv       = ps + NF;                  // N*3F
  float* ys       = pv + NV;                  // N*F
  float* yv       = ys + NF;                  // N*3F
  float* yps      = yv + NV;                  // N*F
  float* ypv      = yps + NF;                 // N*3F
  float* Gs       = ypv + NV;                 // N*F
  float* Gv       = Gs + NF;                  // N*3F
  float* Gps      = Gv + NV;                  // N*F
  float* Gpv      = Gps + NF;                 // N*3F
  float* grad_r   = Gpv + NV;                 // E
  float* grad_u   = grad_r + E_;              // E*3
  float* a_s      = grad_u + (size_t)E_*3;    // 4*N*F
  float* a_v      = a_s + 4*NF;               // 4*N*3F
  float* a_ps     = a_v + 4*NV;               // 4*N*F
  float* a_pv     = a_ps + 4*NF;              // 4*N*3F
  float* a_l      = a_pv + 4*NV;              // N*F
  // int region (CSR + sort)
  int* iws        = (int*)(a_l + NF);
  int* cntd       = iws;                      // N
  int* cnts       = cntd + N_;                // N
  int* dst_off    = cnts + N_;                // N+1
  int* src_off    = dst_off + (N_+1);         // N+1
  int* dst_perm   = src_off + (N_+1);         // E
  int* src_perm   = dst_perm + E_;            // E
  int* curd       = src_perm + E_;            // N
  int* curs       = curd + N_;                // N
  int* binc       = curs + N_;                // 128
  int* bcur       = binc + 128;               // 128
  int* ord_d      = bcur + 128;               // N
  int* ord_s      = ord_d + N_;               // N

  const int TB = 256;
  const int nodeBlocks = (int)(NF / TB);             // 6250 (8 nodes per 256-thr block)
  const int eThreadBlocks = (E_ + TB - 1) / TB;      // 1563
  const int nThreadBlocks = (N_ + TB - 1) / TB;      // 196

  // ---- CSR build + degree sort ----
  fill_int_kernel<<<256, TB, 0, stream>>>(cntd, (size_t)2*N_, 0);
  fill_int_kernel<<<1, 128, 0, stream>>>(binc, 128, 0);
  hist_kernel<<<eThreadBlocks, TB, 0, stream>>>(dst, src, cntd, cnts);
  scan_kernel<<<2, 1024, 0, stream>>>(cntd, cnts, dst_off, src_off);
  cursor_init_kernel<<<nThreadBlocks, TB, 0, stream>>>(dst_off, src_off, curd, curs);
  scatter_kernel<<<eThreadBlocks, TB, 0, stream>>>(dst, src, curd, curs, dst_perm, src_perm);
  sort_hist_kernel<<<nThreadBlocks, TB, 0, stream>>>(dst_off, src_off, binc);
  sort_scan_kernel<<<1, 64, 0, stream>>>(binc, bcur);
  sort_scatter_kernel<<<nThreadBlocks, TB, 0, stream>>>(dst_off, src_off, bcur, ord_d, ord_s);

  // ---- init state + geometry ----
  fill_kernel<<<2048, TB, 0, stream>>>(v, 7*NF, 0.f);  // v,ps,pv = 0
  init_embed_kernel<<<nodeBlocks, TB, 0, stream>>>(s, embed, Z);
  geom_kernel<<<eThreadBlocks, TB, 0, stream>>>(pos, dst, src, rd, u3, rr);

  // ---- 4 full equivariant passes ----
  for (int i = 0; i < 4; ++i) {
    edge_fwd_csr<<<nodeBlocks, TB, 0, stream>>>(
        ord_d, dst_off, dst_perm, src, rd, u3,
        Wb0 + (size_t)i*K_*F_, Wb1 + (size_t)i*K_*F_, pw + (size_t)i*10*F_,
        s, v, ps, pv, ys, yv, yps, ypv);
    node_fwd_kernel<<<nodeBlocks, TB, 0, stream>>>(
        s, v, ps, pv, ys, yv, yps, ypv,
        Wd1 + (size_t)i*4*F_*F_, bd1 + (size_t)i*F_,
        Wd2 + (size_t)i*4*F_*F_, bd2 + (size_t)i*F_,
        a_s + i*NF, a_v + i*NV, a_ps + i*NF, a_pv + i*NV);
  }

  // ---- last scalar pass ----
  fill_kernel<<<592, TB, 0, stream>>>(out, (size_t)(B_ + N_*3), 0.f);
  edge_fwd_last_csr<<<nodeBlocks, TB, 0, stream>>>(
      ord_d, dst_off, dst_perm, src, rd, u3, Wb0l, Wb1l, pwl, s, v, ys);
  node_fwd_last_kernel<<<nodeBlocks, TB, 0, stream>>>(
      s, ys, Wd1l, bd1l, Wd2l, bd2l, a_l, w_out, ebias, Z, bseg, energy);

  // ---- backward init ----
  init_gs_kernel<<<nodeBlocks, TB, 0, stream>>>(Gs, w_out);
  fill_kernel<<<2048, TB, 0, stream>>>(Gv, 7*NF, 0.f);

  // ---- last pass backward (writes grad_r/grad_u, no fill needed) ----
  b1_last_kernel<<<nodeBlocks, TB, 0, stream>>>(s, a_l, Wd1l, Wd2l, bd2l, Gs, ys);
  b2m_last_kernel<<<nodeBlocks, TB, 0, stream>>>(
      ord_s, src_off, src_perm, dst, rd, u3, Wb0l, Wb1l, pwl, s, v, ys,
      Gs, Gv, grad_r, grad_u);

  // ---- 4 full passes backward ----
  for (int i = 3; i >= 0; --i) {
    b1_kernel<<<nodeBlocks, TB, 0, stream>>>(
        s, v, ps, pv,
        a_s + i*NF, a_v + i*NV, a_ps + i*NF, a_pv + i*NV,
        Wd1 + (size_t)i*4*F_*F_, Wd2 + (size_t)i*4*F_*F_, bd2 + (size_t)i*F_,
        Gs, Gv, Gps, Gpv, ys, yv, yps, ypv);
    b2m_kernel<<<nodeBlocks, TB, 0, stream>>>(
        ord_s, src_off, src_perm, dst, rd, u3,
        Wb0 + (size_t)i*K_*F_, Wb1 + (size_t)i*K_*F_, pw + (size_t)i*10*F_,
        s, v, ps, pv, ys, yv, yps, ypv, Gs, Gv, Gps, Gpv, grad_r, grad_u);
  }

  // ---- basis backward -> forces ----
  basis_bwd_kernel<<<eThreadBlocks, TB, 0, stream>>>(
      dst, src, rr, u3, grad_r, grad_u, forces);
}